// Round 5
// baseline (731.818 us; speedup 1.0000x reference)
//
#include <hip/hip_runtime.h>
#include <math.h>

#define NN 10000
#define NE 160000
#define EPB 8            // edges per message block
#define MT 256           // message block threads

namespace {
// MP_PATHS in reference order
constexpr int kL1[11] = {0,0,0,1,1,1,1,2,2,2,2};
constexpr int kL2[11] = {0,1,2,0,1,1,2,0,1,2,2};
constexpr int kL3[11] = {0,1,2,1,0,2,1,2,1,0,2};
// ((l1*3+l2)*3+l3) per path (W slab index)
constexpr int kWOFF[11] = {0,5,7,10,12,14,16,20,22,24,26};
// TD_PATHS in reference order
constexpr int tL1[7] = {0,0,1,1,1,2,2};
constexpr int tL2[7] = {0,1,0,1,2,1,2};
constexpr int tL3[7] = {0,1,1,0,1,1,0};
constexpr int kOFF[3] = {0,1,4};
constexpr int kWID[3] = {1,3,5};

// compile-time (t,i) -> tv-slot tables and c -> (r, tv-slot) tables.
// c ordering matches the (path, i, k) nesting of the reference loop exactly.
struct TVT { unsigned char t[35], p[35]; };
constexpr TVT makeTV() {
  TVT v{};
  int ti = 0;
  for (int t = 0; t < 11; ++t)
    for (int i = 0; i < kWID[kL1[t]]; ++i) {
      v.t[ti] = (unsigned char)t;
      v.p[ti] = (unsigned char)(kOFF[kL1[t]] + i);
      ++ti;
    }
  return v;
}
constexpr TVT TV = makeTV();

struct CTb { unsigned char r[116], tv[116]; };
constexpr CTb makeCT() {
  CTb v{};
  int c = 0, ti = 0;
  for (int t = 0; t < 11; ++t)
    for (int i = 0; i < kWID[kL1[t]]; ++i) {
      for (int k = 0; k < kWID[kL3[t]]; ++k) {
        v.r[c]  = (unsigned char)(kOFF[kL3[t]] + k);
        v.tv[c] = (unsigned char)ti;
        ++c;
      }
      ++ti;
    }
  v.r[115] = 0; v.tv[115] = 0;
  return v;
}
constexpr CTb CTC = makeCT();
}

__device__ float GAUNT_d[729];
__device__ unsigned char CT_P_d[115], CT_R_d[115], CT_L2_d[115];

// float32 spherical harmonics component (matches reference _sph_harm numerics)
__device__ __forceinline__ float sphf(int c, float x, float y, float z) {
  const float s3 = 1.7320508075688772f;
  switch (c) {
    case 0: return 1.0f;
    case 1: return x;
    case 2: return y;
    case 3: return z;
    case 4: return s3 * x * y;
    case 5: return s3 * y * z;
    case 6: return 0.5f * (3.0f * z * z - 1.0f);
    case 7: return s3 * x * z;
    default: return 0.5f * s3 * (x * x - y * y);
  }
}

// Gaunt table build: 16 double-trig calls total (staged in LDS), then a
// shared 128pt x 9comp Y table, then 729 threads do pure FMA loops.
__global__ void gaunt_kernel() {
  __shared__ float Ysh[128][9];
  __shared__ double cph[16], sph[16];
  __shared__ double stq[8], tsh[8], wsh[8];
  const int idx = threadIdx.x;
  const double T[8] = {-0.9602898564975363, -0.7966664774136267, -0.5255324099163290, -0.1834346424956498,
                        0.1834346424956498,  0.5255324099163290,  0.7966664774136267,  0.9602898564975363};
  const double Wq[8] = {0.1012285362903763, 0.2223810344533745, 0.3137066458778873, 0.3626837833783620,
                        0.3626837833783620, 0.3137066458778873, 0.2223810344533745, 0.1012285362903763};
  if (idx < 16) {
    double phi = (double)idx * (6.283185307179586 / 16.0);
    cph[idx] = cos(phi);
    sph[idx] = sin(phi);
  }
  if (idx < 8) {
    tsh[idx] = T[idx];
    wsh[idx] = Wq[idx] / 32.0;
    stq[idx] = sqrt(1.0 - T[idx] * T[idx]);
  }
  __syncthreads();
  for (int i = idx; i < 128 * 9; i += 768) {
    int k = i / 9, c = i - k * 9;
    int it = k >> 4, ip = k & 15;
    float xf = (float)(stq[it] * cph[ip]);
    float yf = (float)(stq[it] * sph[ip]);
    float zf = (float)tsh[it];
    Ysh[k][c] = sphf(c, xf, yf, zf);
  }
  __syncthreads();
  if (idx < 729) {
    int p = idx / 81, q = (idx / 9) % 9, r = idx % 9;
    double acc = 0.0;
    for (int k = 0; k < 128; ++k)  // same summation order as reference (it outer, ip inner)
      acc += wsh[k >> 4] * (double)Ysh[k][p] * (double)Ysh[k][q] * (double)Ysh[k][r];
    GAUNT_d[idx] = (fabs(acc) < 1e-10) ? 0.0f : (float)acc;
  }
  if (idx == 0) {
    // coef index -> (p_global, r_global, l2) tables, in (path, i, k) nesting order
    int c = 0;
    for (int t = 0; t < 11; ++t) {
      int l1 = kL1[t], l2 = kL2[t], l3 = kL3[t];
      for (int i = 0; i < kWID[l1]; ++i)
        for (int k = 0; k < kWID[l3]; ++k) {
          CT_P_d[c]  = (unsigned char)(kOFF[l1] + i);
          CT_R_d[c]  = (unsigned char)(kOFF[l3] + k);
          CT_L2_d[c] = (unsigned char)l2;
          ++c;
        }
    }
  }
}

// ---- destination-sorted edge order build ----
__global__ void zero_kernel(int* __restrict__ cnt) {
  int i = blockIdx.x * 256 + threadIdx.x;
  if (i < NN) cnt[i] = 0;
}

__global__ void hist_kernel(const int* __restrict__ dstI, int* __restrict__ cnt) {
  int e = blockIdx.x * 256 + threadIdx.x;
  if (e < NE) atomicAdd(&cnt[dstI[e]], 1);
}

// single-block in-place exclusive scan over wofs (counts -> start offsets)
__global__ void scan_kernel(int* __restrict__ wofs) {
  __shared__ int partial[1024];
  const int tid = threadIdx.x;           // 1024 threads, 10 elements each
  const int base = tid * 10;
  int local[10];
  int s = 0;
  #pragma unroll
  for (int i = 0; i < 10; ++i) {
    int idx = base + i;
    int v = (idx < NN) ? wofs[idx] : 0;
    local[i] = s;                        // exclusive within chunk
    s += v;
  }
  partial[tid] = s;
  __syncthreads();
  for (int off = 1; off < 1024; off <<= 1) {
    int v = (tid >= off) ? partial[tid - off] : 0;
    __syncthreads();
    partial[tid] += v;
    __syncthreads();
  }
  int pre = (tid == 0) ? 0 : partial[tid - 1];
  #pragma unroll
  for (int i = 0; i < 10; ++i) {
    int idx = base + i;
    if (idx < NN) wofs[idx] = pre + local[i];
  }
}

// edge basis, scattered directly into dst-sorted slot order
__global__ void edge_kernel(const float* __restrict__ pos,
                            const int* __restrict__ srcI, const int* __restrict__ dstI,
                            int* __restrict__ wofs, int* __restrict__ ssrc, int* __restrict__ sdst,
                            float* __restrict__ Yb, float* __restrict__ Rb) {
  int e = blockIdx.x * 256 + threadIdx.x;
  if (e >= NE) return;
  int s = srcI[e], d = dstI[e];
  float dx = pos[s * 3 + 0] - pos[d * 3 + 0];
  float dy = pos[s * 3 + 1] - pos[d * 3 + 1];
  float dz = pos[s * 3 + 2] - pos[d * 3 + 2];
  float r2 = dx * dx + dy * dy + dz * dz;
  float r = sqrtf(fmaxf(r2, 1e-12f));
  float inv = 1.0f / r;
  float x = dx * inv, y = dy * inv, z = dz * inv;
  const float s3 = 1.7320508075688772f;
  int sp = atomicAdd(&wofs[d], 1);       // dst-sorted slot
  ssrc[sp] = s;
  sdst[sp] = d;
  Yb[sp * 9 + 0] = 1.0f;
  Yb[sp * 9 + 1] = x;
  Yb[sp * 9 + 2] = y;
  Yb[sp * 9 + 3] = z;
  Yb[sp * 9 + 4] = s3 * x * y;
  Yb[sp * 9 + 5] = s3 * y * z;
  Yb[sp * 9 + 6] = 0.5f * (3.0f * z * z - 1.0f);
  Yb[sp * 9 + 7] = s3 * x * z;
  Yb[sp * 9 + 8] = 0.5f * s3 * (x * x - y * y);
  float rc = fminf(r, 5.0f - 1e-6f);
  float cut = (r < 5.0f) ? expf(-(rc * rc) / ((5.0f - rc) * (5.0f + rc))) : 0.0f;
  float yv = 1.0f / (1.0f + r);
  float om = 1.0f - yv;
  const float binom[8] = {1.f, 7.f, 21.f, 35.f, 35.f, 21.f, 7.f, 1.f};
  float yk[8], ok[8];
  yk[0] = 1.0f; ok[0] = 1.0f;
  #pragma unroll
  for (int k = 1; k < 8; ++k) { yk[k] = yk[k - 1] * yv; ok[k] = ok[k - 1] * om; }
  #pragma unroll
  for (int k = 0; k < 8; ++k) Rb[sp * 8 + k] = binom[k] * yk[k] * ok[7 - k] * cut;
}

// x init + y zero
__global__ void init_kernel(const float* __restrict__ embed, const int* __restrict__ Z,
                            float* __restrict__ xb, float* __restrict__ yb) {
  int idx = blockIdx.x * 256 + threadIdx.x;
  if (idx >= NN * 288) return;
  int n = idx / 288;
  int rem = idx - n * 288;
  int p = rem >> 5, f = rem & 31;
  xb[idx] = (p == 0) ? embed[Z[n] * 32 + f] : 0.0f;
  yb[idx] = 0.0f;
}

// edge-major message pass over dst-sorted edges (EPB edges / block);
// block-level segmented reduction -> ~1.5 atomic segments per block.
// LDS-issue optimized: W read as swizzled b128 (2/path), C as float4 broadcast.
__launch_bounds__(MT)
__global__ void message_kernel(const float* __restrict__ xb, float* __restrict__ yb,
                               const float* __restrict__ Yb, const float* __restrict__ Rb,
                               const float* __restrict__ Wg,
                               const int* __restrict__ ssrc, const int* __restrict__ sdst) {
  __shared__ __align__(16) float Gs[729];
  __shared__ __align__(16) float Ws[11 * 256];   // [t][f][8], XOR-swizzled
  __shared__ __align__(16) float Ys[EPB][9];
  __shared__ __align__(16) float Rs[EPB][8];
  __shared__ __align__(16) float Cs[EPB][116];   // padded to float4 multiple
  __shared__ __align__(16) float Ms[EPB][288];
  __shared__ int Ds[EPB];
  __shared__ int Hs[EPB + 1];
  __shared__ int nseg_s;
  __shared__ unsigned char Tp[115], Tr[115], Tl2[115];
  const int tid = threadIdx.x;
  const int e0 = blockIdx.x * EPB;

  for (int i = tid; i < 729; i += MT) Gs[i] = GAUNT_d[i];
  for (int i = tid; i < 115; i += MT) { Tp[i] = CT_P_d[i]; Tr[i] = CT_R_d[i]; Tl2[i] = CT_L2_d[i]; }
  // W staging: source layout [t][k][f] -> LDS [t][f][8] with bank-balancing XOR
  // swizzle on the low 8 bits: ph = lg ^ (((lg>>5)&7)<<2), lg = f*8+k.
  for (int i = tid; i < 11 * 256; i += MT) {
    int t = i >> 8, s = i & 255;       // s = k*32+f (coalesced global read)
    int f = s & 31, k = s >> 5;
    int lg = f * 8 + k;
    int ph = lg ^ (((lg >> 5) & 7) << 2);
    Ws[t * 256 + ph] = Wg[kWOFF[t] * 256 + s];
  }
  for (int i = tid; i < EPB * 16; i += MT) {
    int le = i >> 4, q = i & 15;
    if (q < 9) Ys[le][q] = Yb[(e0 + le) * 9 + q];
  }
  for (int i = tid; i < EPB * 8; i += MT) Rs[i >> 3][i & 7] = Rb[e0 * 8 + i];
  if (tid < EPB) Ds[tid] = sdst[e0 + tid];
  __syncthreads();

  // issue the x[src] gather early so it hides under the coefficient phase
  const int le = tid >> 5, f = tid & 31;
  const int sn = ssrc[e0 + le];
  float xs[9];
  #pragma unroll
  for (int p = 0; p < 9; ++p) xs[p] = xb[sn * 288 + p * 32 + f];

  // cooperative per-edge coefficients: coef[c] = sum_q G[p, q, r] * Y[q]
  for (int i = tid; i < EPB * 128; i += MT) {
    int ce = i >> 7, c = i & 127;
    if (c < 115) {
      int p = Tp[c], r = Tr[c], l2 = Tl2[c];
      int q0 = (l2 == 0) ? 0 : ((l2 == 1) ? 1 : 4);
      int nq = (l2 == 0) ? 1 : ((l2 == 1) ? 3 : 5);
      float a = 0.0f;
      for (int j = 0; j < nq; ++j) a += Gs[(p * 9 + q0 + j) * 9 + r] * Ys[ce][q0 + j];
      Cs[ce][c] = a;
    }
  }
  if (tid == 0) {
    // segment heads among the EPB sorted edges
    int ns = 0;
    #pragma unroll
    for (int i = 0; i < EPB; ++i)
      if (i == 0 || Ds[i] != Ds[i - 1]) Hs[ns++] = i;
    Hs[ns] = EPB;
    nseg_s = ns;
  }
  __syncthreads();

  // rw[t] = sum_k R[k] * W[t,k,f] — 2 x ds_read_b128 per path (swizzled layout)
  const float4 R0 = *(const float4*)&Rs[le][0];
  const float4 R1 = *(const float4*)&Rs[le][4];
  const int fb = f * 8;
  const int sx = ((f >> 2) & 7) << 2;
  float rw[11];
  #pragma unroll
  for (int t = 0; t < 11; ++t) {
    const float* base = &Ws[t * 256];
    const float4 w0 = *(const float4*)&base[(fb + 0) ^ sx];
    const float4 w1 = *(const float4*)&base[(fb + 4) ^ sx];
    rw[t] = R0.x * w0.x + R0.y * w0.y + R0.z * w0.z + R0.w * w0.w
          + R1.x * w1.x + R1.y * w1.y + R1.z * w1.z + R1.w * w1.w;
  }

  // tv[ti] = rw[t] * xs[p] for each (path, i) pair — compile-time table
  float tv[35];
  #pragma unroll
  for (int j = 0; j < 35; ++j) tv[j] = rw[TV.t[j]] * xs[TV.p[j]];

  // msg[r] += C[c] * tv[ti(c)] — C read as float4 broadcast (29 reads)
  float msg[9] = {0.f, 0.f, 0.f, 0.f, 0.f, 0.f, 0.f, 0.f, 0.f};
  const float4* C4 = (const float4*)&Cs[le][0];
  #pragma unroll
  for (int c4 = 0; c4 < 29; ++c4) {
    const float4 cc = C4[c4];
    const int c = c4 * 4;
    msg[CTC.r[c]] += cc.x * tv[CTC.tv[c]];
    if (c + 1 < 115) msg[CTC.r[c + 1]] += cc.y * tv[CTC.tv[c + 1]];
    if (c + 2 < 115) msg[CTC.r[c + 2]] += cc.z * tv[CTC.tv[c + 2]];
    if (c + 3 < 115) msg[CTC.r[c + 3]] += cc.w * tv[CTC.tv[c + 3]];
  }
  #pragma unroll
  for (int rr = 0; rr < 9; ++rr) Ms[le][rr * 32 + f] = msg[rr];
  __syncthreads();

  // segmented reduction over the (sorted) EPB edges; one atomic per segment-element
  const int nseg = nseg_s;
  for (int i = tid; i < nseg * 288; i += MT) {
    int s = i / 288, rf = i - s * 288;
    int h = Hs[s], hend = Hs[s + 1];
    float a = 0.0f;
    for (int e = h; e < hend; ++e) a += Ms[e][rf];
    atomicAdd(&yb[Ds[h] * 288 + rf], a);
  }
}

// fused dense1 + silu_e3 + dense2 + residual, one block per node.
// reads x + msg(yb), re-zeroes yb for the next message pass.
__global__ void dense_kernel(float* __restrict__ ybuf, float* __restrict__ xb,
                             const float* __restrict__ W1, const float* __restrict__ b1,
                             const float* __restrict__ W2, const float* __restrict__ b2) {
  __shared__ float yn[288];
  __shared__ float act[288];
  __shared__ float sb[32];
  const int n = blockIdx.x;
  const int tid = threadIdx.x;  // p*32+g, 288 threads
  const int p = tid >> 5, g = tid & 31;
  const float xv = xb[n * 288 + tid];
  const float yv = ybuf[n * 288 + tid];
  ybuf[n * 288 + tid] = 0.0f;          // zero for next iteration's atomics
  yn[tid] = xv + yv;
  __syncthreads();
  const int dg = (p == 0) ? 0 : ((p < 4) ? 1 : 2);
  float a = (p == 0) ? b1[g] : 0.0f;
  #pragma unroll
  for (int f = 0; f < 32; ++f) a += yn[p * 32 + f] * W1[(dg * 32 + f) * 32 + g];
  if (p == 0) sb[g] = a;
  __syncthreads();
  float s = sb[g];
  float sg = 1.0f / (1.0f + expf(-s));
  float v = (p == 0) ? s * sg : a * (sg * (1.0f + s * (1.0f - sg)));
  act[tid] = v;
  __syncthreads();
  float o = (p == 0) ? b2[g] : 0.0f;
  #pragma unroll
  for (int f = 0; f < 32; ++f) o += act[p * 32 + f] * W2[(dg * 32 + f) * 32 + g];
  xb[n * 288 + tid] = xv + o;
}

// tensor_dense + mono/dipo outputs, one block (128 thr) per node; tid = r*32+f, r in 0..3
__global__ void final_kernel(const float* __restrict__ xb, const float* __restrict__ tdW,
                             const float* __restrict__ monoW, const float* __restrict__ ebias,
                             const int* __restrict__ Z, float* __restrict__ out) {
  __shared__ float xl[288];
  __shared__ float B[4][32];
  __shared__ float cb[16];
  const int n = blockIdx.x;
  const int tid = threadIdx.x;
  const int r = tid >> 5, f = tid & 31;
  for (int i = tid; i < 288; i += 128) xl[i] = xb[n * 288 + i];
  __syncthreads();
  float creg = 0.0f;  // c[r][g=f] accumulator, valid on f<4 threads
  #pragma unroll
  for (int t = 0; t < 7; ++t) {
    const int l1 = tL1[t], l2 = tL2[t], l3 = tL3[t];
    const bool active = (l3 == 0) ? (r == 0) : (r >= 1);
    float b = 0.0f;
    if (active) {
      #pragma unroll
      for (int i = 0; i < kWID[l1]; ++i) {
        const int p = kOFF[l1] + i;
        float xp = xl[p * 32 + f];
        #pragma unroll
        for (int j = 0; j < kWID[l2]; ++j) {
          const int q = kOFF[l2] + j;
          b += GAUNT_d[(p * 9 + q) * 9 + r] * xp * xl[q * 32 + f];
        }
      }
    }
    B[r][f] = b;
    __syncthreads();
    if (f < 4 && active) {
      const float* w = tdW + ((l1 * 3 + l2) * 2 + l3) * 128;
      float acc = 0.0f;
      #pragma unroll
      for (int f2 = 0; f2 < 32; ++f2) acc += B[r][f2] * w[f2 * 4 + f];
      creg += acc;
    }
    __syncthreads();
  }
  if (f < 4) cb[r * 4 + f] = creg;
  __syncthreads();
  if (tid < 4) {
    int g = tid;
    float m = 0.0f;
    #pragma unroll
    for (int j = 0; j < 4; ++j) m += cb[j] * monoW[j * 4 + g];
    out[n * 4 + g] = m + ebias[Z[n]];
  }
  if (tid < 12) {
    int row = tid / 4 + 1, g = tid % 4;
    float s = cb[g];
    float gate = (s > -1.0f && s < 1.0f) ? 1.0f : 0.0f;
    out[NN * 4 + n * 12 + (row - 1) * 4 + g] = cb[row * 4 + g] * gate * 0.3f;
  }
}

extern "C" void kernel_launch(void* const* d_in, const int* in_sizes, int n_in,
                              void* d_out, int out_size, void* d_ws, size_t ws_size,
                              hipStream_t stream) {
  const float* positions = (const float*)d_in[0];
  const float* embed     = (const float*)d_in[1];
  const float* mpW       = (const float*)d_in[2];   // (3,3,3,3,8,32)
  const float* d1W       = (const float*)d_in[3];   // (3,3,32,32)
  const float* d1b       = (const float*)d_in[4];   // (3,32)
  const float* d2W       = (const float*)d_in[5];
  const float* d2b       = (const float*)d_in[6];
  const float* tdW       = (const float*)d_in[7];   // (3,3,2,32,4)
  const float* monoW     = (const float*)d_in[8];   // (4,4)
  const float* ebias     = (const float*)d_in[9];   // (18,)
  const int* Z   = (const int*)d_in[10];
  const int* dst = (const int*)d_in[11];
  const int* src = (const int*)d_in[12];
  float* out = (float*)d_out;

  float* Yb = (float*)d_ws;                 // NE*9  (dst-sorted)
  float* Rb = Yb + (size_t)NE * 9;          // NE*8  (dst-sorted)
  float* xb = Rb + (size_t)NE * 8;          // NN*288
  float* yb = xb + (size_t)NN * 288;        // NN*288
  int* ssrc = (int*)(yb + (size_t)NN * 288);  // NE  (dst-sorted src ids)
  int* sdst = ssrc + NE;                    // NE  (sorted dst ids)
  int* wofs = sdst + NE;                    // NN  (hist counters -> scatter cursors)

  gaunt_kernel<<<1, 768, 0, stream>>>();
  zero_kernel<<<(NN + 255) / 256, 256, 0, stream>>>(wofs);
  hist_kernel<<<NE / 256, 256, 0, stream>>>(dst, wofs);
  scan_kernel<<<1, 1024, 0, stream>>>(wofs);
  edge_kernel<<<NE / 256, 256, 0, stream>>>(positions, src, dst, wofs, ssrc, sdst, Yb, Rb);
  init_kernel<<<(NN * 288 + 255) / 256, 256, 0, stream>>>(embed, Z, xb, yb);

  for (int it = 0; it < 3; ++it) {
    message_kernel<<<NE / EPB, MT, 0, stream>>>(xb, yb, Yb, Rb, mpW + (size_t)it * 27 * 256, ssrc, sdst);
    dense_kernel<<<NN, 288, 0, stream>>>(yb, xb, d1W + (size_t)it * 3 * 1024, d1b + it * 32,
                                         d2W + (size_t)it * 3 * 1024, d2b + it * 32);
  }
  final_kernel<<<NN, 128, 0, stream>>>(xb, tdW, monoW, ebias, Z, out);
}

// Round 6
// 678.014 us; speedup vs baseline: 1.0794x; 1.0794x over previous
//
#include <hip/hip_runtime.h>
#include <math.h>

#define NN 10000
#define NE 160000
#define EPB 8            // edges per message block
#define MT 256           // message block threads

namespace {
// MP_PATHS in reference order
constexpr int kL1[11] = {0,0,0,1,1,1,1,2,2,2,2};
constexpr int kL2[11] = {0,1,2,0,1,1,2,0,1,2,2};
constexpr int kL3[11] = {0,1,2,1,0,2,1,2,1,0,2};
// ((l1*3+l2)*3+l3) per path (W slab index)
constexpr int kWOFF[11] = {0,5,7,10,12,14,16,20,22,24,26};
// TD_PATHS in reference order
constexpr int tL1[7] = {0,0,1,1,1,2,2};
constexpr int tL2[7] = {0,1,0,1,2,1,2};
constexpr int tL3[7] = {0,1,1,0,1,1,0};
constexpr int kOFF[3] = {0,1,4};
constexpr int kWID[3] = {1,3,5};

// compile-time (t,i) -> tv-slot tables and c -> (r, tv-slot) tables.
// c ordering matches the (path, i, k) nesting of the reference loop exactly.
struct TVT { unsigned char t[35], p[35]; };
constexpr TVT makeTV() {
  TVT v{};
  int ti = 0;
  for (int t = 0; t < 11; ++t)
    for (int i = 0; i < kWID[kL1[t]]; ++i) {
      v.t[ti] = (unsigned char)t;
      v.p[ti] = (unsigned char)(kOFF[kL1[t]] + i);
      ++ti;
    }
  return v;
}
constexpr TVT TV = makeTV();

struct CTb { unsigned char r[116], tv[116]; };
constexpr CTb makeCT() {
  CTb v{};
  int c = 0, ti = 0;
  for (int t = 0; t < 11; ++t)
    for (int i = 0; i < kWID[kL1[t]]; ++i) {
      for (int k = 0; k < kWID[kL3[t]]; ++k) {
        v.r[c]  = (unsigned char)(kOFF[kL3[t]] + k);
        v.tv[c] = (unsigned char)ti;
        ++c;
      }
      ++ti;
    }
  v.r[115] = 0; v.tv[115] = 0;
  return v;
}
constexpr CTb CTC = makeCT();
}

__device__ float GAUNT_d[729];
__device__ unsigned char CT_P_d[115], CT_R_d[115], CT_L2_d[115];

// float32 spherical harmonics component (matches reference _sph_harm numerics)
__device__ __forceinline__ float sphf(int c, float x, float y, float z) {
  const float s3 = 1.7320508075688772f;
  switch (c) {
    case 0: return 1.0f;
    case 1: return x;
    case 2: return y;
    case 3: return z;
    case 4: return s3 * x * y;
    case 5: return s3 * y * z;
    case 6: return 0.5f * (3.0f * z * z - 1.0f);
    case 7: return s3 * x * z;
    default: return 0.5f * s3 * (x * x - y * y);
  }
}

// Gaunt table build: 16 double-trig calls total (staged in LDS), then a
// shared 128pt x 9comp Y table, then 729 threads do pure FMA loops.
__global__ void gaunt_kernel() {
  __shared__ float Ysh[128][9];
  __shared__ double cph[16], sph[16];
  __shared__ double stq[8], tsh[8], wsh[8];
  const int idx = threadIdx.x;
  const double T[8] = {-0.9602898564975363, -0.7966664774136267, -0.5255324099163290, -0.1834346424956498,
                        0.1834346424956498,  0.5255324099163290,  0.7966664774136267,  0.9602898564975363};
  const double Wq[8] = {0.1012285362903763, 0.2223810344533745, 0.3137066458778873, 0.3626837833783620,
                        0.3626837833783620, 0.3137066458778873, 0.2223810344533745, 0.1012285362903763};
  if (idx < 16) {
    double phi = (double)idx * (6.283185307179586 / 16.0);
    cph[idx] = cos(phi);
    sph[idx] = sin(phi);
  }
  if (idx < 8) {
    tsh[idx] = T[idx];
    wsh[idx] = Wq[idx] / 32.0;
    stq[idx] = sqrt(1.0 - T[idx] * T[idx]);
  }
  __syncthreads();
  for (int i = idx; i < 128 * 9; i += 768) {
    int k = i / 9, c = i - k * 9;
    int it = k >> 4, ip = k & 15;
    float xf = (float)(stq[it] * cph[ip]);
    float yf = (float)(stq[it] * sph[ip]);
    float zf = (float)tsh[it];
    Ysh[k][c] = sphf(c, xf, yf, zf);
  }
  __syncthreads();
  if (idx < 729) {
    int p = idx / 81, q = (idx / 9) % 9, r = idx % 9;
    double acc = 0.0;
    for (int k = 0; k < 128; ++k)  // same summation order as reference (it outer, ip inner)
      acc += wsh[k >> 4] * (double)Ysh[k][p] * (double)Ysh[k][q] * (double)Ysh[k][r];
    GAUNT_d[idx] = (fabs(acc) < 1e-10) ? 0.0f : (float)acc;
  }
  if (idx == 0) {
    // coef index -> (p_global, r_global, l2) tables, in (path, i, k) nesting order
    int c = 0;
    for (int t = 0; t < 11; ++t) {
      int l1 = kL1[t], l2 = kL2[t], l3 = kL3[t];
      for (int i = 0; i < kWID[l1]; ++i)
        for (int k = 0; k < kWID[l3]; ++k) {
          CT_P_d[c]  = (unsigned char)(kOFF[l1] + i);
          CT_R_d[c]  = (unsigned char)(kOFF[l3] + k);
          CT_L2_d[c] = (unsigned char)l2;
          ++c;
        }
    }
  }
}

// ---- destination-sorted edge order build ----
__global__ void zero_kernel(int* __restrict__ cnt) {
  int i = blockIdx.x * 256 + threadIdx.x;
  if (i < NN) cnt[i] = 0;
}

__global__ void hist_kernel(const int* __restrict__ dstI, int* __restrict__ cnt) {
  int e = blockIdx.x * 256 + threadIdx.x;
  if (e < NE) atomicAdd(&cnt[dstI[e]], 1);
}

// single-block in-place exclusive scan over wofs (counts -> start offsets)
__global__ void scan_kernel(int* __restrict__ wofs) {
  __shared__ int partial[1024];
  const int tid = threadIdx.x;           // 1024 threads, 10 elements each
  const int base = tid * 10;
  int local[10];
  int s = 0;
  #pragma unroll
  for (int i = 0; i < 10; ++i) {
    int idx = base + i;
    int v = (idx < NN) ? wofs[idx] : 0;
    local[i] = s;                        // exclusive within chunk
    s += v;
  }
  partial[tid] = s;
  __syncthreads();
  for (int off = 1; off < 1024; off <<= 1) {
    int v = (tid >= off) ? partial[tid - off] : 0;
    __syncthreads();
    partial[tid] += v;
    __syncthreads();
  }
  int pre = (tid == 0) ? 0 : partial[tid - 1];
  #pragma unroll
  for (int i = 0; i < 10; ++i) {
    int idx = base + i;
    if (idx < NN) wofs[idx] = pre + local[i];
  }
}

// edge basis, scattered directly into dst-sorted slot order
__global__ void edge_kernel(const float* __restrict__ pos,
                            const int* __restrict__ srcI, const int* __restrict__ dstI,
                            int* __restrict__ wofs, int* __restrict__ ssrc, int* __restrict__ sdst,
                            float* __restrict__ Yb, float* __restrict__ Rb) {
  int e = blockIdx.x * 256 + threadIdx.x;
  if (e >= NE) return;
  int s = srcI[e], d = dstI[e];
  float dx = pos[s * 3 + 0] - pos[d * 3 + 0];
  float dy = pos[s * 3 + 1] - pos[d * 3 + 1];
  float dz = pos[s * 3 + 2] - pos[d * 3 + 2];
  float r2 = dx * dx + dy * dy + dz * dz;
  float r = sqrtf(fmaxf(r2, 1e-12f));
  float inv = 1.0f / r;
  float x = dx * inv, y = dy * inv, z = dz * inv;
  const float s3 = 1.7320508075688772f;
  int sp = atomicAdd(&wofs[d], 1);       // dst-sorted slot
  ssrc[sp] = s;
  sdst[sp] = d;
  Yb[sp * 9 + 0] = 1.0f;
  Yb[sp * 9 + 1] = x;
  Yb[sp * 9 + 2] = y;
  Yb[sp * 9 + 3] = z;
  Yb[sp * 9 + 4] = s3 * x * y;
  Yb[sp * 9 + 5] = s3 * y * z;
  Yb[sp * 9 + 6] = 0.5f * (3.0f * z * z - 1.0f);
  Yb[sp * 9 + 7] = s3 * x * z;
  Yb[sp * 9 + 8] = 0.5f * s3 * (x * x - y * y);
  float rc = fminf(r, 5.0f - 1e-6f);
  float cut = (r < 5.0f) ? expf(-(rc * rc) / ((5.0f - rc) * (5.0f + rc))) : 0.0f;
  float yv = 1.0f / (1.0f + r);
  float om = 1.0f - yv;
  const float binom[8] = {1.f, 7.f, 21.f, 35.f, 35.f, 21.f, 7.f, 1.f};
  float yk[8], ok[8];
  yk[0] = 1.0f; ok[0] = 1.0f;
  #pragma unroll
  for (int k = 1; k < 8; ++k) { yk[k] = yk[k - 1] * yv; ok[k] = ok[k - 1] * om; }
  #pragma unroll
  for (int k = 0; k < 8; ++k) Rb[sp * 8 + k] = binom[k] * yk[k] * ok[7 - k] * cut;
}

// x init + y zero
__global__ void init_kernel(const float* __restrict__ embed, const int* __restrict__ Z,
                            float* __restrict__ xb, float* __restrict__ yb) {
  int idx = blockIdx.x * 256 + threadIdx.x;
  if (idx >= NN * 288) return;
  int n = idx / 288;
  int rem = idx - n * 288;
  int p = rem >> 5, f = rem & 31;
  xb[idx] = (p == 0) ? embed[Z[n] * 32 + f] : 0.0f;
  yb[idx] = 0.0f;
}

// edge-major message pass over dst-sorted edges (EPB edges / block);
// block-level segmented reduction -> ~1.5 atomic segments per block.
// LDS-issue optimized: W as split [t][f][4] arrays -> conflict-free b128
// (16B-stride consecutive lanes), C as float4 broadcast.
__launch_bounds__(MT)
__global__ void message_kernel(const float* __restrict__ xb, float* __restrict__ yb,
                               const float* __restrict__ Yb, const float* __restrict__ Rb,
                               const float* __restrict__ Wg,
                               const int* __restrict__ ssrc, const int* __restrict__ sdst) {
  __shared__ __align__(16) float Gs[729];
  __shared__ __align__(16) float Wk0[11 * 128];  // [t][f][4], k=0..3
  __shared__ __align__(16) float Wk1[11 * 128];  // [t][f][4], k=4..7
  __shared__ __align__(16) float Ys[EPB][9];
  __shared__ __align__(16) float Rs[EPB][8];
  __shared__ __align__(16) float Cs[EPB][116];   // padded to float4 multiple
  __shared__ __align__(16) float Ms[EPB][288];
  __shared__ int Ds[EPB];
  __shared__ int Hs[EPB + 1];
  __shared__ int nseg_s;
  __shared__ unsigned char Tp[115], Tr[115], Tl2[115];
  const int tid = threadIdx.x;
  const int e0 = blockIdx.x * EPB;

  for (int i = tid; i < 729; i += MT) Gs[i] = GAUNT_d[i];
  for (int i = tid; i < 115; i += MT) { Tp[i] = CT_P_d[i]; Tr[i] = CT_R_d[i]; Tl2[i] = CT_L2_d[i]; }
  // W staging: source layout [t][k][f] (coalesced read) -> split-k LDS [t][f][4]
  for (int i = tid; i < 11 * 256; i += MT) {
    int t = i >> 8, s = i & 255;       // s = k*32+f
    int f = s & 31, k = s >> 5;
    float v = Wg[kWOFF[t] * 256 + s];
    if (k < 4) Wk0[t * 128 + f * 4 + k] = v;
    else       Wk1[t * 128 + f * 4 + (k - 4)] = v;
  }
  for (int i = tid; i < EPB * 16; i += MT) {
    int le = i >> 4, q = i & 15;
    if (q < 9) Ys[le][q] = Yb[(e0 + le) * 9 + q];
  }
  for (int i = tid; i < EPB * 8; i += MT) Rs[i >> 3][i & 7] = Rb[e0 * 8 + i];
  if (tid < EPB) Ds[tid] = sdst[e0 + tid];
  __syncthreads();

  // issue the x[src] gather early so it hides under the coefficient phase
  const int le = tid >> 5, f = tid & 31;
  const int sn = ssrc[e0 + le];
  float xs[9];
  #pragma unroll
  for (int p = 0; p < 9; ++p) xs[p] = xb[sn * 288 + p * 32 + f];

  // cooperative per-edge coefficients: coef[c] = sum_q G[p, q, r] * Y[q]
  for (int i = tid; i < EPB * 128; i += MT) {
    int ce = i >> 7, c = i & 127;
    if (c < 115) {
      int p = Tp[c], r = Tr[c], l2 = Tl2[c];
      int q0 = (l2 == 0) ? 0 : ((l2 == 1) ? 1 : 4);
      int nq = (l2 == 0) ? 1 : ((l2 == 1) ? 3 : 5);
      float a = 0.0f;
      for (int j = 0; j < nq; ++j) a += Gs[(p * 9 + q0 + j) * 9 + r] * Ys[ce][q0 + j];
      Cs[ce][c] = a;
    }
  }
  if (tid == 0) {
    // segment heads among the EPB sorted edges
    int ns = 0;
    #pragma unroll
    for (int i = 0; i < EPB; ++i)
      if (i == 0 || Ds[i] != Ds[i - 1]) Hs[ns++] = i;
    Hs[ns] = EPB;
    nseg_s = ns;
  }
  __syncthreads();

  // rw[t] = sum_k R[k] * W[t,k,f] — 2 conflict-free ds_read_b128 per path
  const float4 R0 = *(const float4*)&Rs[le][0];
  const float4 R1 = *(const float4*)&Rs[le][4];
  const int f4 = f * 4;
  float rw[11];
  #pragma unroll
  for (int t = 0; t < 11; ++t) {
    const float4 w0 = *(const float4*)&Wk0[t * 128 + f4];
    const float4 w1 = *(const float4*)&Wk1[t * 128 + f4];
    rw[t] = R0.x * w0.x + R0.y * w0.y + R0.z * w0.z + R0.w * w0.w
          + R1.x * w1.x + R1.y * w1.y + R1.z * w1.z + R1.w * w1.w;
  }

  // tv[ti] = rw[t] * xs[p] for each (path, i) pair — compile-time table
  float tv[35];
  #pragma unroll
  for (int j = 0; j < 35; ++j) tv[j] = rw[TV.t[j]] * xs[TV.p[j]];

  // msg[r] += C[c] * tv[ti(c)] — C read as float4 broadcast (29 reads)
  float msg[9] = {0.f, 0.f, 0.f, 0.f, 0.f, 0.f, 0.f, 0.f, 0.f};
  const float4* C4 = (const float4*)&Cs[le][0];
  #pragma unroll
  for (int c4 = 0; c4 < 29; ++c4) {
    const float4 cc = C4[c4];
    const int c = c4 * 4;
    msg[CTC.r[c]] += cc.x * tv[CTC.tv[c]];
    if (c + 1 < 115) msg[CTC.r[c + 1]] += cc.y * tv[CTC.tv[c + 1]];
    if (c + 2 < 115) msg[CTC.r[c + 2]] += cc.z * tv[CTC.tv[c + 2]];
    if (c + 3 < 115) msg[CTC.r[c + 3]] += cc.w * tv[CTC.tv[c + 3]];
  }
  #pragma unroll
  for (int rr = 0; rr < 9; ++rr) Ms[le][rr * 32 + f] = msg[rr];
  __syncthreads();

  // segmented reduction over the (sorted) EPB edges; one atomic per segment-element
  const int nseg = nseg_s;
  for (int i = tid; i < nseg * 288; i += MT) {
    int s = i / 288, rf = i - s * 288;
    int h = Hs[s], hend = Hs[s + 1];
    float a = 0.0f;
    for (int e = h; e < hend; ++e) a += Ms[e][rf];
    atomicAdd(&yb[Ds[h] * 288 + rf], a);
  }
}

// fused dense1 + silu_e3 + dense2 + residual, one block per node.
// reads x + msg(yb), re-zeroes yb for the next message pass.
__global__ void dense_kernel(float* __restrict__ ybuf, float* __restrict__ xb,
                             const float* __restrict__ W1, const float* __restrict__ b1,
                             const float* __restrict__ W2, const float* __restrict__ b2) {
  __shared__ float yn[288];
  __shared__ float act[288];
  __shared__ float sb[32];
  const int n = blockIdx.x;
  const int tid = threadIdx.x;  // p*32+g, 288 threads
  const int p = tid >> 5, g = tid & 31;
  const float xv = xb[n * 288 + tid];
  const float yv = ybuf[n * 288 + tid];
  ybuf[n * 288 + tid] = 0.0f;          // zero for next iteration's atomics
  yn[tid] = xv + yv;
  __syncthreads();
  const int dg = (p == 0) ? 0 : ((p < 4) ? 1 : 2);
  float a = (p == 0) ? b1[g] : 0.0f;
  #pragma unroll
  for (int f = 0; f < 32; ++f) a += yn[p * 32 + f] * W1[(dg * 32 + f) * 32 + g];
  if (p == 0) sb[g] = a;
  __syncthreads();
  float s = sb[g];
  float sg = 1.0f / (1.0f + expf(-s));
  float v = (p == 0) ? s * sg : a * (sg * (1.0f + s * (1.0f - sg)));
  act[tid] = v;
  __syncthreads();
  float o = (p == 0) ? b2[g] : 0.0f;
  #pragma unroll
  for (int f = 0; f < 32; ++f) o += act[p * 32 + f] * W2[(dg * 32 + f) * 32 + g];
  xb[n * 288 + tid] = xv + o;
}

// tensor_dense + mono/dipo outputs, one block (128 thr) per node; tid = r*32+f, r in 0..3
__global__ void final_kernel(const float* __restrict__ xb, const float* __restrict__ tdW,
                             const float* __restrict__ monoW, const float* __restrict__ ebias,
                             const int* __restrict__ Z, float* __restrict__ out) {
  __shared__ float xl[288];
  __shared__ float B[4][32];
  __shared__ float cb[16];
  const int n = blockIdx.x;
  const int tid = threadIdx.x;
  const int r = tid >> 5, f = tid & 31;
  for (int i = tid; i < 288; i += 128) xl[i] = xb[n * 288 + i];
  __syncthreads();
  float creg = 0.0f;  // c[r][g=f] accumulator, valid on f<4 threads
  #pragma unroll
  for (int t = 0; t < 7; ++t) {
    const int l1 = tL1[t], l2 = tL2[t], l3 = tL3[t];
    const bool active = (l3 == 0) ? (r == 0) : (r >= 1);
    float b = 0.0f;
    if (active) {
      #pragma unroll
      for (int i = 0; i < kWID[l1]; ++i) {
        const int p = kOFF[l1] + i;
        float xp = xl[p * 32 + f];
        #pragma unroll
        for (int j = 0; j < kWID[l2]; ++j) {
          const int q = kOFF[l2] + j;
          b += GAUNT_d[(p * 9 + q) * 9 + r] * xp * xl[q * 32 + f];
        }
      }
    }
    B[r][f] = b;
    __syncthreads();
    if (f < 4 && active) {
      const float* w = tdW + ((l1 * 3 + l2) * 2 + l3) * 128;
      float acc = 0.0f;
      #pragma unroll
      for (int f2 = 0; f2 < 32; ++f2) acc += B[r][f2] * w[f2 * 4 + f];
      creg += acc;
    }
    __syncthreads();
  }
  if (f < 4) cb[r * 4 + f] = creg;
  __syncthreads();
  if (tid < 4) {
    int g = tid;
    float m = 0.0f;
    #pragma unroll
    for (int j = 0; j < 4; ++j) m += cb[j] * monoW[j * 4 + g];
    out[n * 4 + g] = m + ebias[Z[n]];
  }
  if (tid < 12) {
    int row = tid / 4 + 1, g = tid % 4;
    float s = cb[g];
    float gate = (s > -1.0f && s < 1.0f) ? 1.0f : 0.0f;
    out[NN * 4 + n * 12 + (row - 1) * 4 + g] = cb[row * 4 + g] * gate * 0.3f;
  }
}

extern "C" void kernel_launch(void* const* d_in, const int* in_sizes, int n_in,
                              void* d_out, int out_size, void* d_ws, size_t ws_size,
                              hipStream_t stream) {
  const float* positions = (const float*)d_in[0];
  const float* embed     = (const float*)d_in[1];
  const float* mpW       = (const float*)d_in[2];   // (3,3,3,3,8,32)
  const float* d1W       = (const float*)d_in[3];   // (3,3,32,32)
  const float* d1b       = (const float*)d_in[4];   // (3,32)
  const float* d2W       = (const float*)d_in[5];
  const float* d2b       = (const float*)d_in[6];
  const float* tdW       = (const float*)d_in[7];   // (3,3,2,32,4)
  const float* monoW     = (const float*)d_in[8];   // (4,4)
  const float* ebias     = (const float*)d_in[9];   // (18,)
  const int* Z   = (const int*)d_in[10];
  const int* dst = (const int*)d_in[11];
  const int* src = (const int*)d_in[12];
  float* out = (float*)d_out;

  float* Yb = (float*)d_ws;                 // NE*9  (dst-sorted)
  float* Rb = Yb + (size_t)NE * 9;          // NE*8  (dst-sorted)
  float* xb = Rb + (size_t)NE * 8;          // NN*288
  float* yb = xb + (size_t)NN * 288;        // NN*288
  int* ssrc = (int*)(yb + (size_t)NN * 288);  // NE  (dst-sorted src ids)
  int* sdst = ssrc + NE;                    // NE  (sorted dst ids)
  int* wofs = sdst + NE;                    // NN  (hist counters -> scatter cursors)

  gaunt_kernel<<<1, 768, 0, stream>>>();
  zero_kernel<<<(NN + 255) / 256, 256, 0, stream>>>(wofs);
  hist_kernel<<<NE / 256, 256, 0, stream>>>(dst, wofs);
  scan_kernel<<<1, 1024, 0, stream>>>(wofs);
  edge_kernel<<<NE / 256, 256, 0, stream>>>(positions, src, dst, wofs, ssrc, sdst, Yb, Rb);
  init_kernel<<<(NN * 288 + 255) / 256, 256, 0, stream>>>(embed, Z, xb, yb);

  for (int it = 0; it < 3; ++it) {
    message_kernel<<<NE / EPB, MT, 0, stream>>>(xb, yb, Yb, Rb, mpW + (size_t)it * 27 * 256, ssrc, sdst);
    dense_kernel<<<NN, 288, 0, stream>>>(yb, xb, d1W + (size_t)it * 3 * 1024, d1b + it * 32,
                                         d2W + (size_t)it * 3 * 1024, d2b + it * 32);
  }
  final_kernel<<<NN, 128, 0, stream>>>(xb, tdW, monoW, ebias, Z, out);
}

// Round 7
// 451.220 us; speedup vs baseline: 1.6219x; 1.5026x over previous
//
#include <hip/hip_runtime.h>
#include <math.h>

#define NN 10000
#define NE 160000
#define EPB 8            // edges per message block
#define MT 256           // message block threads
#define CEPB 16          // edges per coef block

namespace {
// MP_PATHS in reference order
constexpr int kL1[11] = {0,0,0,1,1,1,1,2,2,2,2};
constexpr int kL2[11] = {0,1,2,0,1,1,2,0,1,2,2};
constexpr int kL3[11] = {0,1,2,1,0,2,1,2,1,0,2};
// ((l1*3+l2)*3+l3) per path (W slab index)
constexpr int kWOFF[11] = {0,5,7,10,12,14,16,20,22,24,26};
// TD_PATHS in reference order
constexpr int tL1[7] = {0,0,1,1,1,2,2};
constexpr int tL2[7] = {0,1,0,1,2,1,2};
constexpr int tL3[7] = {0,1,1,0,1,1,0};
constexpr int kOFF[3] = {0,1,4};
constexpr int kWID[3] = {1,3,5};

// compile-time (t,i) -> tv-slot tables and c -> (r, tv-slot) tables.
// c ordering matches the (path, i, k) nesting of the reference loop exactly.
struct TVT { unsigned char t[35], p[35]; };
constexpr TVT makeTV() {
  TVT v{};
  int ti = 0;
  for (int t = 0; t < 11; ++t)
    for (int i = 0; i < kWID[kL1[t]]; ++i) {
      v.t[ti] = (unsigned char)t;
      v.p[ti] = (unsigned char)(kOFF[kL1[t]] + i);
      ++ti;
    }
  return v;
}
constexpr TVT TV = makeTV();

struct CTb { unsigned char r[116], tv[116]; };
constexpr CTb makeCT() {
  CTb v{};
  int c = 0, ti = 0;
  for (int t = 0; t < 11; ++t)
    for (int i = 0; i < kWID[kL1[t]]; ++i) {
      for (int k = 0; k < kWID[kL3[t]]; ++k) {
        v.r[c]  = (unsigned char)(kOFF[kL3[t]] + k);
        v.tv[c] = (unsigned char)ti;
        ++c;
      }
      ++ti;
    }
  v.r[115] = 0; v.tv[115] = 0;
  return v;
}
constexpr CTb CTC = makeCT();
}

__device__ float GAUNT_d[729];
__device__ unsigned char CT_P_d[115], CT_R_d[115], CT_L2_d[115];

// float32 spherical harmonics component (matches reference _sph_harm numerics)
__device__ __forceinline__ float sphf(int c, float x, float y, float z) {
  const float s3 = 1.7320508075688772f;
  switch (c) {
    case 0: return 1.0f;
    case 1: return x;
    case 2: return y;
    case 3: return z;
    case 4: return s3 * x * y;
    case 5: return s3 * y * z;
    case 6: return 0.5f * (3.0f * z * z - 1.0f);
    case 7: return s3 * x * z;
    default: return 0.5f * s3 * (x * x - y * y);
  }
}

// Gaunt table build: 16 double-trig calls total (staged in LDS), then a
// shared 128pt x 9comp Y table, then 729 threads do pure FMA loops.
__global__ void gaunt_kernel() {
  __shared__ float Ysh[128][9];
  __shared__ double cph[16], sph[16];
  __shared__ double stq[8], tsh[8], wsh[8];
  const int idx = threadIdx.x;
  const double T[8] = {-0.9602898564975363, -0.7966664774136267, -0.5255324099163290, -0.1834346424956498,
                        0.1834346424956498,  0.5255324099163290,  0.7966664774136267,  0.9602898564975363};
  const double Wq[8] = {0.1012285362903763, 0.2223810344533745, 0.3137066458778873, 0.3626837833783620,
                        0.3626837833783620, 0.3137066458778873, 0.2223810344533745, 0.1012285362903763};
  if (idx < 16) {
    double phi = (double)idx * (6.283185307179586 / 16.0);
    cph[idx] = cos(phi);
    sph[idx] = sin(phi);
  }
  if (idx < 8) {
    tsh[idx] = T[idx];
    wsh[idx] = Wq[idx] / 32.0;
    stq[idx] = sqrt(1.0 - T[idx] * T[idx]);
  }
  __syncthreads();
  for (int i = idx; i < 128 * 9; i += 768) {
    int k = i / 9, c = i - k * 9;
    int it = k >> 4, ip = k & 15;
    float xf = (float)(stq[it] * cph[ip]);
    float yf = (float)(stq[it] * sph[ip]);
    float zf = (float)tsh[it];
    Ysh[k][c] = sphf(c, xf, yf, zf);
  }
  __syncthreads();
  if (idx < 729) {
    int p = idx / 81, q = (idx / 9) % 9, r = idx % 9;
    double acc = 0.0;
    for (int k = 0; k < 128; ++k)  // same summation order as reference (it outer, ip inner)
      acc += wsh[k >> 4] * (double)Ysh[k][p] * (double)Ysh[k][q] * (double)Ysh[k][r];
    GAUNT_d[idx] = (fabs(acc) < 1e-10) ? 0.0f : (float)acc;
  }
  if (idx == 0) {
    // coef index -> (p_global, r_global, l2) tables, in (path, i, k) nesting order
    int c = 0;
    for (int t = 0; t < 11; ++t) {
      int l1 = kL1[t], l2 = kL2[t], l3 = kL3[t];
      for (int i = 0; i < kWID[l1]; ++i)
        for (int k = 0; k < kWID[l3]; ++k) {
          CT_P_d[c]  = (unsigned char)(kOFF[l1] + i);
          CT_R_d[c]  = (unsigned char)(kOFF[l3] + k);
          CT_L2_d[c] = (unsigned char)l2;
          ++c;
        }
    }
  }
}

// ---- destination-sorted edge order build ----
__global__ void zero_kernel(int* __restrict__ cnt) {
  int i = blockIdx.x * 256 + threadIdx.x;
  if (i < NN) cnt[i] = 0;
}

__global__ void hist_kernel(const int* __restrict__ dstI, int* __restrict__ cnt) {
  int e = blockIdx.x * 256 + threadIdx.x;
  if (e < NE) atomicAdd(&cnt[dstI[e]], 1);
}

// single-block in-place exclusive scan over wofs (counts -> start offsets)
__global__ void scan_kernel(int* __restrict__ wofs) {
  __shared__ int partial[1024];
  const int tid = threadIdx.x;           // 1024 threads, 10 elements each
  const int base = tid * 10;
  int local[10];
  int s = 0;
  #pragma unroll
  for (int i = 0; i < 10; ++i) {
    int idx = base + i;
    int v = (idx < NN) ? wofs[idx] : 0;
    local[i] = s;                        // exclusive within chunk
    s += v;
  }
  partial[tid] = s;
  __syncthreads();
  for (int off = 1; off < 1024; off <<= 1) {
    int v = (tid >= off) ? partial[tid - off] : 0;
    __syncthreads();
    partial[tid] += v;
    __syncthreads();
  }
  int pre = (tid == 0) ? 0 : partial[tid - 1];
  #pragma unroll
  for (int i = 0; i < 10; ++i) {
    int idx = base + i;
    if (idx < NN) wofs[idx] = pre + local[i];
  }
}

// edge basis, scattered directly into dst-sorted slot order
__global__ void edge_kernel(const float* __restrict__ pos,
                            const int* __restrict__ srcI, const int* __restrict__ dstI,
                            int* __restrict__ wofs, int* __restrict__ ssrc, int* __restrict__ sdst,
                            float* __restrict__ Yb, float* __restrict__ Rb) {
  int e = blockIdx.x * 256 + threadIdx.x;
  if (e >= NE) return;
  int s = srcI[e], d = dstI[e];
  float dx = pos[s * 3 + 0] - pos[d * 3 + 0];
  float dy = pos[s * 3 + 1] - pos[d * 3 + 1];
  float dz = pos[s * 3 + 2] - pos[d * 3 + 2];
  float r2 = dx * dx + dy * dy + dz * dz;
  float r = sqrtf(fmaxf(r2, 1e-12f));
  float inv = 1.0f / r;
  float x = dx * inv, y = dy * inv, z = dz * inv;
  const float s3 = 1.7320508075688772f;
  int sp = atomicAdd(&wofs[d], 1);       // dst-sorted slot
  ssrc[sp] = s;
  sdst[sp] = d;
  Yb[sp * 9 + 0] = 1.0f;
  Yb[sp * 9 + 1] = x;
  Yb[sp * 9 + 2] = y;
  Yb[sp * 9 + 3] = z;
  Yb[sp * 9 + 4] = s3 * x * y;
  Yb[sp * 9 + 5] = s3 * y * z;
  Yb[sp * 9 + 6] = 0.5f * (3.0f * z * z - 1.0f);
  Yb[sp * 9 + 7] = s3 * x * z;
  Yb[sp * 9 + 8] = 0.5f * s3 * (x * x - y * y);
  float rc = fminf(r, 5.0f - 1e-6f);
  float cut = (r < 5.0f) ? expf(-(rc * rc) / ((5.0f - rc) * (5.0f + rc))) : 0.0f;
  float yv = 1.0f / (1.0f + r);
  float om = 1.0f - yv;
  const float binom[8] = {1.f, 7.f, 21.f, 35.f, 35.f, 21.f, 7.f, 1.f};
  float yk[8], ok[8];
  yk[0] = 1.0f; ok[0] = 1.0f;
  #pragma unroll
  for (int k = 1; k < 8; ++k) { yk[k] = yk[k - 1] * yv; ok[k] = ok[k - 1] * om; }
  #pragma unroll
  for (int k = 0; k < 8; ++k) Rb[sp * 8 + k] = binom[k] * yk[k] * ok[7 - k] * cut;
}

// per-edge Gaunt-contracted coefficients, computed ONCE (iteration-independent):
// Cb[e][c] = sum_q G[p(c), q, r(c)] * Y[e][q], padded to 116 floats/row
__global__ void coef_kernel(const float* __restrict__ Yb, float* __restrict__ Cb) {
  __shared__ float Gs[729];
  __shared__ float Ys[CEPB][9];
  __shared__ unsigned char Tp[115], Tr[115], Tl2[115];
  const int tid = threadIdx.x;
  const int e0 = blockIdx.x * CEPB;
  for (int i = tid; i < 729; i += 256) Gs[i] = GAUNT_d[i];
  for (int i = tid; i < 115; i += 256) { Tp[i] = CT_P_d[i]; Tr[i] = CT_R_d[i]; Tl2[i] = CT_L2_d[i]; }
  for (int i = tid; i < CEPB * 9; i += 256) Ys[i / 9][i % 9] = Yb[e0 * 9 + i];
  __syncthreads();
  for (int i = tid; i < CEPB * 128; i += 256) {
    int ce = i >> 7, c = i & 127;
    if (c < 116) {
      float a = 0.0f;
      if (c < 115) {
        int p = Tp[c], r = Tr[c], l2 = Tl2[c];
        int q0 = (l2 == 0) ? 0 : ((l2 == 1) ? 1 : 4);
        int nq = (l2 == 0) ? 1 : ((l2 == 1) ? 3 : 5);
        for (int j = 0; j < nq; ++j) a += Gs[(p * 9 + q0 + j) * 9 + r] * Ys[ce][q0 + j];
      }
      Cb[(size_t)(e0 + ce) * 116 + c] = a;
    }
  }
}

// x init + y zero
__global__ void init_kernel(const float* __restrict__ embed, const int* __restrict__ Z,
                            float* __restrict__ xb, float* __restrict__ yb) {
  int idx = blockIdx.x * 256 + threadIdx.x;
  if (idx >= NN * 288) return;
  int n = idx / 288;
  int rem = idx - n * 288;
  int p = rem >> 5, f = rem & 31;
  xb[idx] = (p == 0) ? embed[Z[n] * 32 + f] : 0.0f;
  yb[idx] = 0.0f;
}

// edge-major message pass over dst-sorted edges (EPB edges / block), with
// precomputed per-edge C staged via coalesced float4 loads; W in the proven
// conflict-free scalar-broadcast layout. 2 barriers, ~24.5KB LDS -> 6 blk/CU.
__launch_bounds__(MT)
__global__ void message_kernel(const float* __restrict__ xb, float* __restrict__ yb,
                               const float* __restrict__ Rb, const float* __restrict__ Cb,
                               const float* __restrict__ Wg,
                               const int* __restrict__ ssrc, const int* __restrict__ sdst) {
  __shared__ __align__(16) float Ws[11 * 256];   // [t][k*32+f] -- r3 layout
  __shared__ __align__(16) float4 Cs4[EPB][29];
  __shared__ __align__(16) float Rs[EPB][8];
  __shared__ __align__(16) float Ms[EPB][288];
  __shared__ int Ds[EPB];
  __shared__ int Hs[EPB + 1];
  __shared__ int nseg_s;
  const int tid = threadIdx.x;
  const int e0 = blockIdx.x * EPB;

  #pragma unroll
  for (int t = 0; t < 11; ++t) {
    const int off = kWOFF[t] * 256;
    Ws[t * 256 + tid] = Wg[off + tid];
  }
  if (tid < EPB * 29) {    // 232 coalesced float4 loads
    const float4* Cbv = (const float4*)Cb;
    ((float4*)Cs4)[tid] = Cbv[(size_t)e0 * 29 + tid];
  }
  for (int i = tid; i < EPB * 8; i += MT) Rs[i >> 3][i & 7] = Rb[e0 * 8 + i];
  if (tid < EPB) Ds[tid] = sdst[e0 + tid];
  __syncthreads();

  // issue the x[src] gather early so it hides under rw compute
  const int le = tid >> 5, f = tid & 31;
  const int sn = ssrc[e0 + le];
  float xs[9];
  #pragma unroll
  for (int p = 0; p < 9; ++p) xs[p] = xb[sn * 288 + p * 32 + f];

  if (tid == 0) {
    // segment heads among the EPB sorted edges (consumed after next barrier)
    int ns = 0;
    #pragma unroll
    for (int i = 0; i < EPB; ++i)
      if (i == 0 || Ds[i] != Ds[i - 1]) Hs[ns++] = i;
    Hs[ns] = EPB;
    nseg_s = ns;
  }

  // rw[t] = sum_k R[k] * W[t,k,f] — conflict-free (lane=f spans 32 banks;
  // upper half-wave broadcasts the same addresses)
  const float4 R0 = *(const float4*)&Rs[le][0];
  const float4 R1 = *(const float4*)&Rs[le][4];
  float rw[11];
  #pragma unroll
  for (int t = 0; t < 11; ++t) {
    const float* base = &Ws[t * 256];
    rw[t] = R0.x * base[f] + R0.y * base[32 + f] + R0.z * base[64 + f] + R0.w * base[96 + f]
          + R1.x * base[128 + f] + R1.y * base[160 + f] + R1.z * base[192 + f] + R1.w * base[224 + f];
  }

  // tv[ti] = rw[t] * xs[p] for each (path, i) pair — compile-time table
  float tv[35];
  #pragma unroll
  for (int j = 0; j < 35; ++j) tv[j] = rw[TV.t[j]] * xs[TV.p[j]];

  // msg[r] += C[c] * tv[ti(c)] — C read as float4 broadcast (29 reads)
  float msg[9] = {0.f, 0.f, 0.f, 0.f, 0.f, 0.f, 0.f, 0.f, 0.f};
  #pragma unroll
  for (int c4 = 0; c4 < 29; ++c4) {
    const float4 cc = Cs4[le][c4];
    const int c = c4 * 4;
    msg[CTC.r[c]] += cc.x * tv[CTC.tv[c]];
    if (c + 1 < 115) msg[CTC.r[c + 1]] += cc.y * tv[CTC.tv[c + 1]];
    if (c + 2 < 115) msg[CTC.r[c + 2]] += cc.z * tv[CTC.tv[c + 2]];
    if (c + 3 < 115) msg[CTC.r[c + 3]] += cc.w * tv[CTC.tv[c + 3]];
  }
  #pragma unroll
  for (int rr = 0; rr < 9; ++rr) Ms[le][rr * 32 + f] = msg[rr];
  __syncthreads();

  // segmented reduction over the (sorted) EPB edges; one atomic per segment-element
  const int nseg = nseg_s;
  for (int i = tid; i < nseg * 288; i += MT) {
    int s = i / 288, rf = i - s * 288;
    int h = Hs[s], hend = Hs[s + 1];
    float a = 0.0f;
    for (int e = h; e < hend; ++e) a += Ms[e][rf];
    atomicAdd(&yb[Ds[h] * 288 + rf], a);
  }
}

// fallback (in-kernel coef, round-3 form) used if workspace is too small for Cb
__launch_bounds__(MT)
__global__ void message_kernel_ic(const float* __restrict__ xb, float* __restrict__ yb,
                                  const float* __restrict__ Yb, const float* __restrict__ Rb,
                                  const float* __restrict__ Wg,
                                  const int* __restrict__ ssrc, const int* __restrict__ sdst) {
  __shared__ float Gs[729];
  __shared__ float Ws[11 * 256];
  __shared__ float Ys[EPB][9];
  __shared__ float Rs[EPB][8];
  __shared__ float Cs[EPB][116];
  __shared__ float Ms[EPB][288];
  __shared__ int Ds[EPB];
  __shared__ int Hs[EPB + 1];
  __shared__ int nseg_s;
  __shared__ unsigned char Tp[115], Tr[115], Tl2[115];
  const int tid = threadIdx.x;
  const int e0 = blockIdx.x * EPB;

  for (int i = tid; i < 729; i += MT) Gs[i] = GAUNT_d[i];
  for (int i = tid; i < 115; i += MT) { Tp[i] = CT_P_d[i]; Tr[i] = CT_R_d[i]; Tl2[i] = CT_L2_d[i]; }
  #pragma unroll
  for (int t = 0; t < 11; ++t) Ws[t * 256 + tid] = Wg[kWOFF[t] * 256 + tid];
  for (int i = tid; i < EPB * 16; i += MT) {
    int le = i >> 4, q = i & 15;
    if (q < 9) Ys[le][q] = Yb[(e0 + le) * 9 + q];
  }
  for (int i = tid; i < EPB * 8; i += MT) Rs[i >> 3][i & 7] = Rb[e0 * 8 + i];
  if (tid < EPB) Ds[tid] = sdst[e0 + tid];
  __syncthreads();

  const int le = tid >> 5, f = tid & 31;
  const int sn = ssrc[e0 + le];
  float xs[9];
  #pragma unroll
  for (int p = 0; p < 9; ++p) xs[p] = xb[sn * 288 + p * 32 + f];

  for (int i = tid; i < EPB * 128; i += MT) {
    int ce = i >> 7, c = i & 127;
    if (c < 115) {
      int p = Tp[c], r = Tr[c], l2 = Tl2[c];
      int q0 = (l2 == 0) ? 0 : ((l2 == 1) ? 1 : 4);
      int nq = (l2 == 0) ? 1 : ((l2 == 1) ? 3 : 5);
      float a = 0.0f;
      for (int j = 0; j < nq; ++j) a += Gs[(p * 9 + q0 + j) * 9 + r] * Ys[ce][q0 + j];
      Cs[ce][c] = a;
    }
  }
  if (tid == 0) {
    int ns = 0;
    #pragma unroll
    for (int i = 0; i < EPB; ++i)
      if (i == 0 || Ds[i] != Ds[i - 1]) Hs[ns++] = i;
    Hs[ns] = EPB;
    nseg_s = ns;
  }
  __syncthreads();

  const float4 R0 = *(const float4*)&Rs[le][0];
  const float4 R1 = *(const float4*)&Rs[le][4];
  float rw[11];
  #pragma unroll
  for (int t = 0; t < 11; ++t) {
    const float* base = &Ws[t * 256];
    rw[t] = R0.x * base[f] + R0.y * base[32 + f] + R0.z * base[64 + f] + R0.w * base[96 + f]
          + R1.x * base[128 + f] + R1.y * base[160 + f] + R1.z * base[192 + f] + R1.w * base[224 + f];
  }
  float tv[35];
  #pragma unroll
  for (int j = 0; j < 35; ++j) tv[j] = rw[TV.t[j]] * xs[TV.p[j]];
  float msg[9] = {0.f, 0.f, 0.f, 0.f, 0.f, 0.f, 0.f, 0.f, 0.f};
  #pragma unroll
  for (int c = 0; c < 115; ++c) msg[CTC.r[c]] += Cs[le][c] * tv[CTC.tv[c]];
  #pragma unroll
  for (int rr = 0; rr < 9; ++rr) Ms[le][rr * 32 + f] = msg[rr];
  __syncthreads();

  const int nseg = nseg_s;
  for (int i = tid; i < nseg * 288; i += MT) {
    int s = i / 288, rf = i - s * 288;
    int h = Hs[s], hend = Hs[s + 1];
    float a = 0.0f;
    for (int e = h; e < hend; ++e) a += Ms[e][rf];
    atomicAdd(&yb[Ds[h] * 288 + rf], a);
  }
}

// fused dense1 + silu_e3 + dense2 + residual, one block per node.
// reads x + msg(yb), re-zeroes yb for the next message pass.
__global__ void dense_kernel(float* __restrict__ ybuf, float* __restrict__ xb,
                             const float* __restrict__ W1, const float* __restrict__ b1,
                             const float* __restrict__ W2, const float* __restrict__ b2) {
  __shared__ float yn[288];
  __shared__ float act[288];
  __shared__ float sb[32];
  const int n = blockIdx.x;
  const int tid = threadIdx.x;  // p*32+g, 288 threads
  const int p = tid >> 5, g = tid & 31;
  const float xv = xb[n * 288 + tid];
  const float yv = ybuf[n * 288 + tid];
  ybuf[n * 288 + tid] = 0.0f;          // zero for next iteration's atomics
  yn[tid] = xv + yv;
  __syncthreads();
  const int dg = (p == 0) ? 0 : ((p < 4) ? 1 : 2);
  float a = (p == 0) ? b1[g] : 0.0f;
  #pragma unroll
  for (int f = 0; f < 32; ++f) a += yn[p * 32 + f] * W1[(dg * 32 + f) * 32 + g];
  if (p == 0) sb[g] = a;
  __syncthreads();
  float s = sb[g];
  float sg = 1.0f / (1.0f + expf(-s));
  float v = (p == 0) ? s * sg : a * (sg * (1.0f + s * (1.0f - sg)));
  act[tid] = v;
  __syncthreads();
  float o = (p == 0) ? b2[g] : 0.0f;
  #pragma unroll
  for (int f = 0; f < 32; ++f) o += act[p * 32 + f] * W2[(dg * 32 + f) * 32 + g];
  xb[n * 288 + tid] = xv + o;
}

// tensor_dense + mono/dipo outputs, one block (128 thr) per node; tid = r*32+f, r in 0..3
__global__ void final_kernel(const float* __restrict__ xb, const float* __restrict__ tdW,
                             const float* __restrict__ monoW, const float* __restrict__ ebias,
                             const int* __restrict__ Z, float* __restrict__ out) {
  __shared__ float xl[288];
  __shared__ float B[4][32];
  __shared__ float cb[16];
  const int n = blockIdx.x;
  const int tid = threadIdx.x;
  const int r = tid >> 5, f = tid & 31;
  for (int i = tid; i < 288; i += 128) xl[i] = xb[n * 288 + i];
  __syncthreads();
  float creg = 0.0f;  // c[r][g=f] accumulator, valid on f<4 threads
  #pragma unroll
  for (int t = 0; t < 7; ++t) {
    const int l1 = tL1[t], l2 = tL2[t], l3 = tL3[t];
    const bool active = (l3 == 0) ? (r == 0) : (r >= 1);
    float b = 0.0f;
    if (active) {
      #pragma unroll
      for (int i = 0; i < kWID[l1]; ++i) {
        const int p = kOFF[l1] + i;
        float xp = xl[p * 32 + f];
        #pragma unroll
        for (int j = 0; j < kWID[l2]; ++j) {
          const int q = kOFF[l2] + j;
          b += GAUNT_d[(p * 9 + q) * 9 + r] * xp * xl[q * 32 + f];
        }
      }
    }
    B[r][f] = b;
    __syncthreads();
    if (f < 4 && active) {
      const float* w = tdW + ((l1 * 3 + l2) * 2 + l3) * 128;
      float acc = 0.0f;
      #pragma unroll
      for (int f2 = 0; f2 < 32; ++f2) acc += B[r][f2] * w[f2 * 4 + f];
      creg += acc;
    }
    __syncthreads();
  }
  if (f < 4) cb[r * 4 + f] = creg;
  __syncthreads();
  if (tid < 4) {
    int g = tid;
    float m = 0.0f;
    #pragma unroll
    for (int j = 0; j < 4; ++j) m += cb[j] * monoW[j * 4 + g];
    out[n * 4 + g] = m + ebias[Z[n]];
  }
  if (tid < 12) {
    int row = tid / 4 + 1, g = tid % 4;
    float s = cb[g];
    float gate = (s > -1.0f && s < 1.0f) ? 1.0f : 0.0f;
    out[NN * 4 + n * 12 + (row - 1) * 4 + g] = cb[row * 4 + g] * gate * 0.3f;
  }
}

extern "C" void kernel_launch(void* const* d_in, const int* in_sizes, int n_in,
                              void* d_out, int out_size, void* d_ws, size_t ws_size,
                              hipStream_t stream) {
  const float* positions = (const float*)d_in[0];
  const float* embed     = (const float*)d_in[1];
  const float* mpW       = (const float*)d_in[2];   // (3,3,3,3,8,32)
  const float* d1W       = (const float*)d_in[3];   // (3,3,32,32)
  const float* d1b       = (const float*)d_in[4];   // (3,32)
  const float* d2W       = (const float*)d_in[5];
  const float* d2b       = (const float*)d_in[6];
  const float* tdW       = (const float*)d_in[7];   // (3,3,2,32,4)
  const float* monoW     = (const float*)d_in[8];   // (4,4)
  const float* ebias     = (const float*)d_in[9];   // (18,)
  const int* Z   = (const int*)d_in[10];
  const int* dst = (const int*)d_in[11];
  const int* src = (const int*)d_in[12];
  float* out = (float*)d_out;

  float* Yb = (float*)d_ws;                 // NE*9  (dst-sorted)
  float* Rb = Yb + (size_t)NE * 9;          // NE*8  (dst-sorted)
  float* xb = Rb + (size_t)NE * 8;          // NN*288
  float* yb = xb + (size_t)NN * 288;        // NN*288
  // base footprint without Cb:
  size_t base_f = (size_t)NE * 9 + (size_t)NE * 8 + (size_t)NN * 288 * 2;
  size_t need_pc = (base_f + (size_t)NE * 116) * 4 + ((size_t)NE * 2 + NN) * 4;
  bool pc = ws_size >= need_pc;

  float* Cb = yb + (size_t)NN * 288;        // NE*116 (only if pc)
  float* after = pc ? (Cb + (size_t)NE * 116) : Cb;
  int* ssrc = (int*)after;                  // NE  (dst-sorted src ids)
  int* sdst = ssrc + NE;                    // NE  (sorted dst ids)
  int* wofs = sdst + NE;                    // NN  (hist counters -> scatter cursors)

  gaunt_kernel<<<1, 768, 0, stream>>>();
  zero_kernel<<<(NN + 255) / 256, 256, 0, stream>>>(wofs);
  hist_kernel<<<NE / 256, 256, 0, stream>>>(dst, wofs);
  scan_kernel<<<1, 1024, 0, stream>>>(wofs);
  edge_kernel<<<NE / 256, 256, 0, stream>>>(positions, src, dst, wofs, ssrc, sdst, Yb, Rb);
  if (pc) coef_kernel<<<NE / CEPB, 256, 0, stream>>>(Yb, Cb);
  init_kernel<<<(NN * 288 + 255) / 256, 256, 0, stream>>>(embed, Z, xb, yb);

  for (int it = 0; it < 3; ++it) {
    if (pc)
      message_kernel<<<NE / EPB, MT, 0, stream>>>(xb, yb, Rb, Cb, mpW + (size_t)it * 27 * 256, ssrc, sdst);
    else
      message_kernel_ic<<<NE / EPB, MT, 0, stream>>>(xb, yb, Yb, Rb, mpW + (size_t)it * 27 * 256, ssrc, sdst);
    dense_kernel<<<NN, 288, 0, stream>>>(yb, xb, d1W + (size_t)it * 3 * 1024, d1b + it * 32,
                                         d2W + (size_t)it * 3 * 1024, d2b + it * 32);
  }
  final_kernel<<<NN, 128, 0, stream>>>(xb, tdW, monoW, ebias, Z, out);
}

// Round 8
// 431.052 us; speedup vs baseline: 1.6977x; 1.0468x over previous
//
#include <hip/hip_runtime.h>
#include <math.h>

#define NN 10000
#define NE 160000
#define EPB 8            // edges per message block
#define MT 256           // message block threads
#define CEPB 16          // edges per coef block

namespace {
// MP_PATHS in reference order
constexpr int kL1[11] = {0,0,0,1,1,1,1,2,2,2,2};
constexpr int kL2[11] = {0,1,2,0,1,1,2,0,1,2,2};
constexpr int kL3[11] = {0,1,2,1,0,2,1,2,1,0,2};
// ((l1*3+l2)*3+l3) per path (W slab index)
constexpr int kWOFF[11] = {0,5,7,10,12,14,16,20,22,24,26};
// TD_PATHS in reference order
constexpr int tL1[7] = {0,0,1,1,1,2,2};
constexpr int tL2[7] = {0,1,0,1,2,1,2};
constexpr int tL3[7] = {0,1,1,0,1,1,0};
constexpr int kOFF[3] = {0,1,4};
constexpr int kWID[3] = {1,3,5};

// compile-time (t,i) -> tv-slot tables and c -> (r, tv-slot) tables.
// c ordering matches the (path, i, k) nesting of the reference loop exactly.
struct TVT { unsigned char t[35], p[35]; };
constexpr TVT makeTV() {
  TVT v{};
  int ti = 0;
  for (int t = 0; t < 11; ++t)
    for (int i = 0; i < kWID[kL1[t]]; ++i) {
      v.t[ti] = (unsigned char)t;
      v.p[ti] = (unsigned char)(kOFF[kL1[t]] + i);
      ++ti;
    }
  return v;
}
constexpr TVT TV = makeTV();

struct CTb { unsigned char r[116], tv[116]; };
constexpr CTb makeCT() {
  CTb v{};
  int c = 0, ti = 0;
  for (int t = 0; t < 11; ++t)
    for (int i = 0; i < kWID[kL1[t]]; ++i) {
      for (int k = 0; k < kWID[kL3[t]]; ++k) {
        v.r[c]  = (unsigned char)(kOFF[kL3[t]] + k);
        v.tv[c] = (unsigned char)ti;
        ++c;
      }
      ++ti;
    }
  v.r[115] = 0; v.tv[115] = 0;
  return v;
}
constexpr CTb CTC = makeCT();
}

__device__ float GAUNT_d[729];
__device__ unsigned char CT_P_d[115], CT_R_d[115], CT_L2_d[115];

// float32 spherical harmonics component (matches reference _sph_harm numerics)
__device__ __forceinline__ float sphf(int c, float x, float y, float z) {
  const float s3 = 1.7320508075688772f;
  switch (c) {
    case 0: return 1.0f;
    case 1: return x;
    case 2: return y;
    case 3: return z;
    case 4: return s3 * x * y;
    case 5: return s3 * y * z;
    case 6: return 0.5f * (3.0f * z * z - 1.0f);
    case 7: return s3 * x * z;
    default: return 0.5f * s3 * (x * x - y * y);
  }
}

// Gaunt table build: 16 double-trig calls total (staged in LDS), then a
// shared 128pt x 9comp Y table, then 729 threads do pure FMA loops.
__global__ void gaunt_kernel() {
  __shared__ float Ysh[128][9];
  __shared__ double cph[16], sph[16];
  __shared__ double stq[8], tsh[8], wsh[8];
  const int idx = threadIdx.x;
  const double T[8] = {-0.9602898564975363, -0.7966664774136267, -0.5255324099163290, -0.1834346424956498,
                        0.1834346424956498,  0.5255324099163290,  0.7966664774136267,  0.9602898564975363};
  const double Wq[8] = {0.1012285362903763, 0.2223810344533745, 0.3137066458778873, 0.3626837833783620,
                        0.3626837833783620, 0.3137066458778873, 0.2223810344533745, 0.1012285362903763};
  if (idx < 16) {
    double phi = (double)idx * (6.283185307179586 / 16.0);
    cph[idx] = cos(phi);
    sph[idx] = sin(phi);
  }
  if (idx < 8) {
    tsh[idx] = T[idx];
    wsh[idx] = Wq[idx] / 32.0;
    stq[idx] = sqrt(1.0 - T[idx] * T[idx]);
  }
  __syncthreads();
  for (int i = idx; i < 128 * 9; i += 768) {
    int k = i / 9, c = i - k * 9;
    int it = k >> 4, ip = k & 15;
    float xf = (float)(stq[it] * cph[ip]);
    float yf = (float)(stq[it] * sph[ip]);
    float zf = (float)tsh[it];
    Ysh[k][c] = sphf(c, xf, yf, zf);
  }
  __syncthreads();
  if (idx < 729) {
    int p = idx / 81, q = (idx / 9) % 9, r = idx % 9;
    double acc = 0.0;
    for (int k = 0; k < 128; ++k)  // same summation order as reference (it outer, ip inner)
      acc += wsh[k >> 4] * (double)Ysh[k][p] * (double)Ysh[k][q] * (double)Ysh[k][r];
    GAUNT_d[idx] = (fabs(acc) < 1e-10) ? 0.0f : (float)acc;
  }
  if (idx == 0) {
    // coef index -> (p_global, r_global, l2) tables, in (path, i, k) nesting order
    int c = 0;
    for (int t = 0; t < 11; ++t) {
      int l1 = kL1[t], l2 = kL2[t], l3 = kL3[t];
      for (int i = 0; i < kWID[l1]; ++i)
        for (int k = 0; k < kWID[l3]; ++k) {
          CT_P_d[c]  = (unsigned char)(kOFF[l1] + i);
          CT_R_d[c]  = (unsigned char)(kOFF[l3] + k);
          CT_L2_d[c] = (unsigned char)l2;
          ++c;
        }
    }
  }
}

// ---- destination-sorted edge order build ----
__global__ void hist_kernel(const int* __restrict__ dstI, int* __restrict__ cnt) {
  int e = blockIdx.x * 256 + threadIdx.x;
  if (e < NE) atomicAdd(&cnt[dstI[e]], 1);
}

// single-block in-place exclusive scan over wofs (counts -> start offsets)
__global__ void scan_kernel(int* __restrict__ wofs) {
  __shared__ int partial[1024];
  const int tid = threadIdx.x;           // 1024 threads, 10 elements each
  const int base = tid * 10;
  int local[10];
  int s = 0;
  #pragma unroll
  for (int i = 0; i < 10; ++i) {
    int idx = base + i;
    int v = (idx < NN) ? wofs[idx] : 0;
    local[i] = s;                        // exclusive within chunk
    s += v;
  }
  partial[tid] = s;
  __syncthreads();
  for (int off = 1; off < 1024; off <<= 1) {
    int v = (tid >= off) ? partial[tid - off] : 0;
    __syncthreads();
    partial[tid] += v;
    __syncthreads();
  }
  int pre = (tid == 0) ? 0 : partial[tid - 1];
  #pragma unroll
  for (int i = 0; i < 10; ++i) {
    int idx = base + i;
    if (idx < NN) wofs[idx] = pre + local[i];
  }
}

// edge basis, scattered directly into dst-sorted slot order
__global__ void edge_kernel(const float* __restrict__ pos,
                            const int* __restrict__ srcI, const int* __restrict__ dstI,
                            int* __restrict__ wofs, int* __restrict__ ssrc, int* __restrict__ sdst,
                            float* __restrict__ Yb, float* __restrict__ Rb) {
  int e = blockIdx.x * 256 + threadIdx.x;
  if (e >= NE) return;
  int s = srcI[e], d = dstI[e];
  float dx = pos[s * 3 + 0] - pos[d * 3 + 0];
  float dy = pos[s * 3 + 1] - pos[d * 3 + 1];
  float dz = pos[s * 3 + 2] - pos[d * 3 + 2];
  float r2 = dx * dx + dy * dy + dz * dz;
  float r = sqrtf(fmaxf(r2, 1e-12f));
  float inv = 1.0f / r;
  float x = dx * inv, y = dy * inv, z = dz * inv;
  const float s3 = 1.7320508075688772f;
  int sp = atomicAdd(&wofs[d], 1);       // dst-sorted slot
  ssrc[sp] = s;
  sdst[sp] = d;
  Yb[sp * 9 + 0] = 1.0f;
  Yb[sp * 9 + 1] = x;
  Yb[sp * 9 + 2] = y;
  Yb[sp * 9 + 3] = z;
  Yb[sp * 9 + 4] = s3 * x * y;
  Yb[sp * 9 + 5] = s3 * y * z;
  Yb[sp * 9 + 6] = 0.5f * (3.0f * z * z - 1.0f);
  Yb[sp * 9 + 7] = s3 * x * z;
  Yb[sp * 9 + 8] = 0.5f * s3 * (x * x - y * y);
  float rc = fminf(r, 5.0f - 1e-6f);
  float cut = (r < 5.0f) ? expf(-(rc * rc) / ((5.0f - rc) * (5.0f + rc))) : 0.0f;
  float yv = 1.0f / (1.0f + r);
  float om = 1.0f - yv;
  const float binom[8] = {1.f, 7.f, 21.f, 35.f, 35.f, 21.f, 7.f, 1.f};
  float yk[8], ok[8];
  yk[0] = 1.0f; ok[0] = 1.0f;
  #pragma unroll
  for (int k = 1; k < 8; ++k) { yk[k] = yk[k - 1] * yv; ok[k] = ok[k - 1] * om; }
  #pragma unroll
  for (int k = 0; k < 8; ++k) Rb[sp * 8 + k] = binom[k] * yk[k] * ok[7 - k] * cut;
}

// per-edge Gaunt-contracted coefficients, computed ONCE (iteration-independent):
// Cb[e][c] = sum_q G[p(c), q, r(c)] * Y[e][q], padded to 116 floats/row
__global__ void coef_kernel(const float* __restrict__ Yb, float* __restrict__ Cb) {
  __shared__ float Gs[729];
  __shared__ float Ys[CEPB][9];
  __shared__ unsigned char Tp[115], Tr[115], Tl2[115];
  const int tid = threadIdx.x;
  const int e0 = blockIdx.x * CEPB;
  for (int i = tid; i < 729; i += 256) Gs[i] = GAUNT_d[i];
  for (int i = tid; i < 115; i += 256) { Tp[i] = CT_P_d[i]; Tr[i] = CT_R_d[i]; Tl2[i] = CT_L2_d[i]; }
  for (int i = tid; i < CEPB * 9; i += 256) Ys[i / 9][i % 9] = Yb[e0 * 9 + i];
  __syncthreads();
  for (int i = tid; i < CEPB * 128; i += 256) {
    int ce = i >> 7, c = i & 127;
    if (c < 116) {
      float a = 0.0f;
      if (c < 115) {
        int p = Tp[c], r = Tr[c], l2 = Tl2[c];
        int q0 = (l2 == 0) ? 0 : ((l2 == 1) ? 1 : 4);
        int nq = (l2 == 0) ? 1 : ((l2 == 1) ? 3 : 5);
        for (int j = 0; j < nq; ++j) a += Gs[(p * 9 + q0 + j) * 9 + r] * Ys[ce][q0 + j];
      }
      Cb[(size_t)(e0 + ce) * 116 + c] = a;
    }
  }
}

// x init + y zero
__global__ void init_kernel(const float* __restrict__ embed, const int* __restrict__ Z,
                            float* __restrict__ xb, float* __restrict__ yb) {
  int idx = blockIdx.x * 256 + threadIdx.x;
  if (idx >= NN * 288) return;
  int n = idx / 288;
  int rem = idx - n * 288;
  int p = rem >> 5, f = rem & 31;
  xb[idx] = (p == 0) ? embed[Z[n] * 32 + f] : 0.0f;
  yb[idx] = 0.0f;
}

// edge-major message pass over dst-sorted edges (EPB edges / block), with
// precomputed per-edge C staged via coalesced float4 loads; W in the proven
// conflict-free scalar-broadcast layout. Ws/Ms share one LDS array (phase A /
// phase B) -> ~15.3KB LDS -> occupancy cap 32 waves/CU.
__launch_bounds__(MT)
__global__ void message_kernel(const float* __restrict__ xb, float* __restrict__ yb,
                               const float* __restrict__ Rb, const float* __restrict__ Cb,
                               const float* __restrict__ Wg,
                               const int* __restrict__ ssrc, const int* __restrict__ sdst) {
  __shared__ __align__(16) float U[11 * 256];    // phase A: Ws[t][k*32+f]; phase B: Ms[le][288]
  __shared__ __align__(16) float4 Cs4[EPB][29];
  __shared__ __align__(16) float Rs[EPB][8];
  __shared__ int Ds[EPB];
  __shared__ int Hs[EPB + 1];
  __shared__ int nseg_s;
  const int tid = threadIdx.x;
  const int e0 = blockIdx.x * EPB;
  const int le = tid >> 5, f = tid & 31;

  // issue the x[src] gather FIRST (no LDS dependency) so the ~300cy latency
  // hides under the staging stores + barrier
  const int sn = ssrc[e0 + le];
  float xs[9];
  #pragma unroll
  for (int p = 0; p < 9; ++p) xs[p] = xb[sn * 288 + p * 32 + f];

  float* Ws = U;
  #pragma unroll
  for (int t = 0; t < 11; ++t) {
    const int off = kWOFF[t] * 256;
    Ws[t * 256 + tid] = Wg[off + tid];
  }
  if (tid < EPB * 29) {    // 232 coalesced float4 loads
    const float4* Cbv = (const float4*)Cb;
    ((float4*)Cs4)[tid] = Cbv[(size_t)e0 * 29 + tid];
  }
  for (int i = tid; i < EPB * 8; i += MT) Rs[i >> 3][i & 7] = Rb[e0 * 8 + i];
  if (tid < EPB) Ds[tid] = sdst[e0 + tid];
  __syncthreads();

  if (tid == 0) {
    // segment heads among the EPB sorted edges (consumed after next barrier)
    int ns = 0;
    #pragma unroll
    for (int i = 0; i < EPB; ++i)
      if (i == 0 || Ds[i] != Ds[i - 1]) Hs[ns++] = i;
    Hs[ns] = EPB;
    nseg_s = ns;
  }

  // rw[t] = sum_k R[k] * W[t,k,f] — conflict-free (lane=f spans 32 banks;
  // upper half-wave broadcasts the same addresses)
  const float4 R0 = *(const float4*)&Rs[le][0];
  const float4 R1 = *(const float4*)&Rs[le][4];
  float rw[11];
  #pragma unroll
  for (int t = 0; t < 11; ++t) {
    const float* base = &Ws[t * 256];
    rw[t] = R0.x * base[f] + R0.y * base[32 + f] + R0.z * base[64 + f] + R0.w * base[96 + f]
          + R1.x * base[128 + f] + R1.y * base[160 + f] + R1.z * base[192 + f] + R1.w * base[224 + f];
  }

  // tv[ti] = rw[t] * xs[p] for each (path, i) pair — compile-time table
  float tv[35];
  #pragma unroll
  for (int j = 0; j < 35; ++j) tv[j] = rw[TV.t[j]] * xs[TV.p[j]];

  // msg[r] += C[c] * tv[ti(c)] — C read as float4 broadcast (29 reads)
  float msg[9] = {0.f, 0.f, 0.f, 0.f, 0.f, 0.f, 0.f, 0.f, 0.f};
  #pragma unroll
  for (int c4 = 0; c4 < 29; ++c4) {
    const float4 cc = Cs4[le][c4];
    const int c = c4 * 4;
    msg[CTC.r[c]] += cc.x * tv[CTC.tv[c]];
    if (c + 1 < 115) msg[CTC.r[c + 1]] += cc.y * tv[CTC.tv[c + 1]];
    if (c + 2 < 115) msg[CTC.r[c + 2]] += cc.z * tv[CTC.tv[c + 2]];
    if (c + 3 < 115) msg[CTC.r[c + 3]] += cc.w * tv[CTC.tv[c + 3]];
  }

  __syncthreads();                 // all Ws reads done before Ms overwrites U
  float* Ms = U;                   // phase B view
  #pragma unroll
  for (int rr = 0; rr < 9; ++rr) Ms[le * 288 + rr * 32 + f] = msg[rr];
  __syncthreads();

  // segmented reduction over the (sorted) EPB edges; one atomic per segment-element
  const int nseg = nseg_s;
  for (int i = tid; i < nseg * 288; i += MT) {
    int s = i / 288, rf = i - s * 288;
    int h = Hs[s], hend = Hs[s + 1];
    float a = 0.0f;
    for (int e = h; e < hend; ++e) a += Ms[e * 288 + rf];
    atomicAdd(&yb[Ds[h] * 288 + rf], a);
  }
}

// fallback (in-kernel coef, round-3 form) used if workspace is too small for Cb
__launch_bounds__(MT)
__global__ void message_kernel_ic(const float* __restrict__ xb, float* __restrict__ yb,
                                  const float* __restrict__ Yb, const float* __restrict__ Rb,
                                  const float* __restrict__ Wg,
                                  const int* __restrict__ ssrc, const int* __restrict__ sdst) {
  __shared__ float Gs[729];
  __shared__ float Ws[11 * 256];
  __shared__ float Ys[EPB][9];
  __shared__ float Rs[EPB][8];
  __shared__ float Cs[EPB][116];
  __shared__ float Ms[EPB][288];
  __shared__ int Ds[EPB];
  __shared__ int Hs[EPB + 1];
  __shared__ int nseg_s;
  __shared__ unsigned char Tp[115], Tr[115], Tl2[115];
  const int tid = threadIdx.x;
  const int e0 = blockIdx.x * EPB;

  for (int i = tid; i < 729; i += MT) Gs[i] = GAUNT_d[i];
  for (int i = tid; i < 115; i += MT) { Tp[i] = CT_P_d[i]; Tr[i] = CT_R_d[i]; Tl2[i] = CT_L2_d[i]; }
  #pragma unroll
  for (int t = 0; t < 11; ++t) Ws[t * 256 + tid] = Wg[kWOFF[t] * 256 + tid];
  for (int i = tid; i < EPB * 16; i += MT) {
    int le = i >> 4, q = i & 15;
    if (q < 9) Ys[le][q] = Yb[(e0 + le) * 9 + q];
  }
  for (int i = tid; i < EPB * 8; i += MT) Rs[i >> 3][i & 7] = Rb[e0 * 8 + i];
  if (tid < EPB) Ds[tid] = sdst[e0 + tid];
  __syncthreads();

  const int le = tid >> 5, f = tid & 31;
  const int sn = ssrc[e0 + le];
  float xs[9];
  #pragma unroll
  for (int p = 0; p < 9; ++p) xs[p] = xb[sn * 288 + p * 32 + f];

  for (int i = tid; i < EPB * 128; i += MT) {
    int ce = i >> 7, c = i & 127;
    if (c < 115) {
      int p = Tp[c], r = Tr[c], l2 = Tl2[c];
      int q0 = (l2 == 0) ? 0 : ((l2 == 1) ? 1 : 4);
      int nq = (l2 == 0) ? 1 : ((l2 == 1) ? 3 : 5);
      float a = 0.0f;
      for (int j = 0; j < nq; ++j) a += Gs[(p * 9 + q0 + j) * 9 + r] * Ys[ce][q0 + j];
      Cs[ce][c] = a;
    }
  }
  if (tid == 0) {
    int ns = 0;
    #pragma unroll
    for (int i = 0; i < EPB; ++i)
      if (i == 0 || Ds[i] != Ds[i - 1]) Hs[ns++] = i;
    Hs[ns] = EPB;
    nseg_s = ns;
  }
  __syncthreads();

  const float4 R0 = *(const float4*)&Rs[le][0];
  const float4 R1 = *(const float4*)&Rs[le][4];
  float rw[11];
  #pragma unroll
  for (int t = 0; t < 11; ++t) {
    const float* base = &Ws[t * 256];
    rw[t] = R0.x * base[f] + R0.y * base[32 + f] + R0.z * base[64 + f] + R0.w * base[96 + f]
          + R1.x * base[128 + f] + R1.y * base[160 + f] + R1.z * base[192 + f] + R1.w * base[224 + f];
  }
  float tv[35];
  #pragma unroll
  for (int j = 0; j < 35; ++j) tv[j] = rw[TV.t[j]] * xs[TV.p[j]];
  float msg[9] = {0.f, 0.f, 0.f, 0.f, 0.f, 0.f, 0.f, 0.f, 0.f};
  #pragma unroll
  for (int c = 0; c < 115; ++c) msg[CTC.r[c]] += Cs[le][c] * tv[CTC.tv[c]];
  #pragma unroll
  for (int rr = 0; rr < 9; ++rr) Ms[le][rr * 32 + f] = msg[rr];
  __syncthreads();

  const int nseg = nseg_s;
  for (int i = tid; i < nseg * 288; i += MT) {
    int s = i / 288, rf = i - s * 288;
    int h = Hs[s], hend = Hs[s + 1];
    float a = 0.0f;
    for (int e = h; e < hend; ++e) a += Ms[e][rf];
    atomicAdd(&yb[Ds[h] * 288 + rf], a);
  }
}

// fused dense1 + silu_e3 + dense2 + residual, one block per node.
// reads x + msg(yb), re-zeroes yb for the next message pass.
__global__ void dense_kernel(float* __restrict__ ybuf, float* __restrict__ xb,
                             const float* __restrict__ W1, const float* __restrict__ b1,
                             const float* __restrict__ W2, const float* __restrict__ b2) {
  __shared__ float yn[288];
  __shared__ float act[288];
  __shared__ float sb[32];
  const int n = blockIdx.x;
  const int tid = threadIdx.x;  // p*32+g, 288 threads
  const int p = tid >> 5, g = tid & 31;
  const float xv = xb[n * 288 + tid];
  const float yv = ybuf[n * 288 + tid];
  ybuf[n * 288 + tid] = 0.0f;          // zero for next iteration's atomics
  yn[tid] = xv + yv;
  __syncthreads();
  const int dg = (p == 0) ? 0 : ((p < 4) ? 1 : 2);
  float a = (p == 0) ? b1[g] : 0.0f;
  #pragma unroll
  for (int f = 0; f < 32; ++f) a += yn[p * 32 + f] * W1[(dg * 32 + f) * 32 + g];
  if (p == 0) sb[g] = a;
  __syncthreads();
  float s = sb[g];
  float sg = 1.0f / (1.0f + expf(-s));
  float v = (p == 0) ? s * sg : a * (sg * (1.0f + s * (1.0f - sg)));
  act[tid] = v;
  __syncthreads();
  float o = (p == 0) ? b2[g] : 0.0f;
  #pragma unroll
  for (int f = 0; f < 32; ++f) o += act[p * 32 + f] * W2[(dg * 32 + f) * 32 + g];
  xb[n * 288 + tid] = xv + o;
}

// tensor_dense + mono/dipo outputs, one block (128 thr) per node; tid = r*32+f, r in 0..3
__global__ void final_kernel(const float* __restrict__ xb, const float* __restrict__ tdW,
                             const float* __restrict__ monoW, const float* __restrict__ ebias,
                             const int* __restrict__ Z, float* __restrict__ out) {
  __shared__ float xl[288];
  __shared__ float B[4][32];
  __shared__ float cb[16];
  const int n = blockIdx.x;
  const int tid = threadIdx.x;
  const int r = tid >> 5, f = tid & 31;
  for (int i = tid; i < 288; i += 128) xl[i] = xb[n * 288 + i];
  __syncthreads();
  float creg = 0.0f;  // c[r][g=f] accumulator, valid on f<4 threads
  #pragma unroll
  for (int t = 0; t < 7; ++t) {
    const int l1 = tL1[t], l2 = tL2[t], l3 = tL3[t];
    const bool active = (l3 == 0) ? (r == 0) : (r >= 1);
    float b = 0.0f;
    if (active) {
      #pragma unroll
      for (int i = 0; i < kWID[l1]; ++i) {
        const int p = kOFF[l1] + i;
        float xp = xl[p * 32 + f];
        #pragma unroll
        for (int j = 0; j < kWID[l2]; ++j) {
          const int q = kOFF[l2] + j;
          b += GAUNT_d[(p * 9 + q) * 9 + r] * xp * xl[q * 32 + f];
        }
      }
    }
    B[r][f] = b;
    __syncthreads();
    if (f < 4 && active) {
      const float* w = tdW + ((l1 * 3 + l2) * 2 + l3) * 128;
      float acc = 0.0f;
      #pragma unroll
      for (int f2 = 0; f2 < 32; ++f2) acc += B[r][f2] * w[f2 * 4 + f];
      creg += acc;
    }
    __syncthreads();
  }
  if (f < 4) cb[r * 4 + f] = creg;
  __syncthreads();
  if (tid < 4) {
    int g = tid;
    float m = 0.0f;
    #pragma unroll
    for (int j = 0; j < 4; ++j) m += cb[j] * monoW[j * 4 + g];
    out[n * 4 + g] = m + ebias[Z[n]];
  }
  if (tid < 12) {
    int row = tid / 4 + 1, g = tid % 4;
    float s = cb[g];
    float gate = (s > -1.0f && s < 1.0f) ? 1.0f : 0.0f;
    out[NN * 4 + n * 12 + (row - 1) * 4 + g] = cb[row * 4 + g] * gate * 0.3f;
  }
}

extern "C" void kernel_launch(void* const* d_in, const int* in_sizes, int n_in,
                              void* d_out, int out_size, void* d_ws, size_t ws_size,
                              hipStream_t stream) {
  const float* positions = (const float*)d_in[0];
  const float* embed     = (const float*)d_in[1];
  const float* mpW       = (const float*)d_in[2];   // (3,3,3,3,8,32)
  const float* d1W       = (const float*)d_in[3];   // (3,3,32,32)
  const float* d1b       = (const float*)d_in[4];   // (3,32)
  const float* d2W       = (const float*)d_in[5];
  const float* d2b       = (const float*)d_in[6];
  const float* tdW       = (const float*)d_in[7];   // (3,3,2,32,4)
  const float* monoW     = (const float*)d_in[8];   // (4,4)
  const float* ebias     = (const float*)d_in[9];   // (18,)
  const int* Z   = (const int*)d_in[10];
  const int* dst = (const int*)d_in[11];
  const int* src = (const int*)d_in[12];
  float* out = (float*)d_out;

  float* Yb = (float*)d_ws;                 // NE*9  (dst-sorted)
  float* Rb = Yb + (size_t)NE * 9;          // NE*8  (dst-sorted)
  float* xb = Rb + (size_t)NE * 8;          // NN*288
  float* yb = xb + (size_t)NN * 288;        // NN*288
  // base footprint without Cb:
  size_t base_f = (size_t)NE * 9 + (size_t)NE * 8 + (size_t)NN * 288 * 2;
  size_t need_pc = (base_f + (size_t)NE * 116) * 4 + ((size_t)NE * 2 + NN) * 4;
  bool pc = ws_size >= need_pc;

  float* Cb = yb + (size_t)NN * 288;        // NE*116 (only if pc)
  float* after = pc ? (Cb + (size_t)NE * 116) : Cb;
  int* ssrc = (int*)after;                  // NE  (dst-sorted src ids)
  int* sdst = ssrc + NE;                    // NE  (sorted dst ids)
  int* wofs = sdst + NE;                    // NN  (hist counters -> scatter cursors)

  gaunt_kernel<<<1, 768, 0, stream>>>();
  hipMemsetAsync(wofs, 0, NN * sizeof(int), stream);
  hist_kernel<<<NE / 256, 256, 0, stream>>>(dst, wofs);
  scan_kernel<<<1, 1024, 0, stream>>>(wofs);
  edge_kernel<<<NE / 256, 256, 0, stream>>>(positions, src, dst, wofs, ssrc, sdst, Yb, Rb);
  if (pc) coef_kernel<<<NE / CEPB, 256, 0, stream>>>(Yb, Cb);
  init_kernel<<<(NN * 288 + 255) / 256, 256, 0, stream>>>(embed, Z, xb, yb);

  for (int it = 0; it < 3; ++it) {
    if (pc)
      message_kernel<<<NE / EPB, MT, 0, stream>>>(xb, yb, Rb, Cb, mpW + (size_t)it * 27 * 256, ssrc, sdst);
    else
      message_kernel_ic<<<NE / EPB, MT, 0, stream>>>(xb, yb, Yb, Rb, mpW + (size_t)it * 27 * 256, ssrc, sdst);
    dense_kernel<<<NN, 288, 0, stream>>>(yb, xb, d1W + (size_t)it * 3 * 1024, d1b + it * 32,
                                         d2W + (size_t)it * 3 * 1024, d2b + it * 32);
  }
  final_kernel<<<NN, 128, 0, stream>>>(xb, tdW, monoW, ebias, Z, out);
}